// Round 2
// baseline (445.270 us; speedup 1.0000x reference)
//
#include <hip/hip_runtime.h>
#include <hip/hip_bf16.h>

#define TSEQ  4096
#define NBATCH 4
#define CDIM  2048
#define DH    128

typedef __bf16 bf16x8 __attribute__((ext_vector_type(8)));
typedef float  f32x4  __attribute__((ext_vector_type(4)));
typedef unsigned short u16x8 __attribute__((ext_vector_type(8)));
typedef unsigned       u32x4 __attribute__((ext_vector_type(4)));
typedef unsigned short u16;

__device__ __forceinline__ u16 f2bf(float f) {
  union { float f; unsigned u; } v; v.f = f;
  unsigned r = (v.u + 0x7FFFu + ((v.u >> 16) & 1u)) >> 16;
  return (u16)r;
}
__device__ __forceinline__ float bf2f(u16 h) {
  union { unsigned u; float f; } v; v.u = ((unsigned)h) << 16;
  return v.f;
}
__device__ __forceinline__ bf16x8 ld_bf8(const u16* p) {
  return __builtin_bit_cast(bf16x8, *(const u16x8*)p);
}
__device__ __forceinline__ unsigned pk2(float lo, float hi) {
  float2 f; f.x = lo; f.y = hi;
  __hip_bfloat162 h = __float22bfloat162_rn(f);
  unsigned r; __builtin_memcpy(&r, &h, 4);
  return r;
}
__device__ __forceinline__ u16x8 cvt8u(float4 a, float4 b) {
  u32x4 u;
  u[0] = pk2(a.x, a.y); u[1] = pk2(a.z, a.w);
  u[2] = pk2(b.x, b.y); u[3] = pk2(b.z, b.w);
  return __builtin_bit_cast(u16x8, u);
}

// raw workgroup barrier: drains LDS (lgkmcnt) only, NOT vmcnt — keeps global
// prefetch loads in flight across the barrier.
__device__ __forceinline__ void lds_barrier() {
  asm volatile("s_waitcnt lgkmcnt(0)" ::: "memory");
  __builtin_amdgcn_s_barrier();
}

// DPP cross-lane (VALU pipe): reduce over each 16-lane row
template<int CTRL>
__device__ __forceinline__ float dppmv(float x) {
  return __builtin_bit_cast(float,
    __builtin_amdgcn_update_dpp(0, __builtin_bit_cast(int, x), CTRL, 0xF, 0xF, true));
}
__device__ __forceinline__ float red_max16(float v) {
  v = fmaxf(v, dppmv<0xB1>(v));
  v = fmaxf(v, dppmv<0x4E>(v));
  v = fmaxf(v, dppmv<0x124>(v));
  v = fmaxf(v, dppmv<0x128>(v));
  return v;
}
__device__ __forceinline__ float red_sum16(float v) {
  v += dppmv<0xB1>(v);
  v += dppmv<0x4E>(v);
  v += dppmv<0x124>(v);
  v += dppmv<0x128>(v);
  return v;
}

// unit base within a batch: q-tile Q (128 rows) has (Q>>2)+1 chunks
__device__ __forceinline__ int unit_base(int Q) {
  int a = Q >> 2, bq = Q & 3;
  return 2 * a * (a + 1) + bq * (a + 1);
}

// ---------------- fused kernel 1: vt | ropek | qproj ----------------
// qproj reads w_q fp32 directly (converts to bf16 in-register, bit-identical to
// the old wbf path) -> no dependency on any prep output -> everything fuses
// into one launch. Short prep blocks first, the 512 heavy qproj blocks last.
__global__ __launch_bounds__(256, 2) void k_fused1(const float* __restrict__ w,
                                                   const float* __restrict__ key,
                                                   u16* __restrict__ krot,
                                                   const float* __restrict__ value,
                                                   u16* __restrict__ vt,
                                                   const float* __restrict__ x,
                                                   u16* __restrict__ qrot,
                                                   int* __restrict__ cnt) {
  __shared__ u16 S[128 * 66];            // vt transpose tile; qproj reuses 8 KB of it
  int bid = blockIdx.x;
  int tid = threadIdx.x;

  if (bid < 256) {
    // ---- value transpose [B,T,D] -> [B,D,T] in bf16 ----
    if (bid == 0 && tid < 128) cnt[tid] = 0;   // zero merge counters (attn runs after)
    int b = bid >> 6;
    int t0 = (bid & 63) * 64;
    int d = (tid & 31) * 4;
    int tl0 = tid >> 5;
#pragma unroll
    for (int i = 0; i < 8; ++i) {
      int tl = tl0 + i * 8;
      const float4 val = *(const float4*)(value + ((size_t)(b * TSEQ + t0 + tl)) * DH + d);
      S[(d + 0) * 66 + tl] = f2bf(val.x);
      S[(d + 1) * 66 + tl] = f2bf(val.y);
      S[(d + 2) * 66 + tl] = f2bf(val.z);
      S[(d + 3) * 66 + tl] = f2bf(val.w);
    }
    __syncthreads();
#pragma unroll
    for (int i = 0; i < 16; ++i) {
      int idx = tid + i * 256;
      int dd = idx >> 5;
      int tw = (idx & 31) * 2;
      unsigned lo = S[dd * 66 + tw];
      unsigned hi = S[dd * 66 + tw + 1];
      *(unsigned*)(vt + ((size_t)(b * DH + dd)) * TSEQ + t0 + tw) = lo | (hi << 16);
    }
    return;
  }

  if (bid < 2304) {
    // ---- RoPE on key, 16 B/thread (2 pairs), fp32 -> bf16 ----
    int idx = (bid - 256) * 256 + tid;   // float4 index
    int f0 = idx * 4;
    int row = f0 >> 7;                   // /DH (floats per row)
    int d = f0 & 127;
    int p = d >> 1;                      // even pair index; handles p and p+1
    int t = row & (TSEQ - 1);
    const float4 kv = *(const float4*)(key + (size_t)row * DH + d);
    float inv0 = powf(10000.0f, -(float)p / 64.0f);
    float inv1 = powf(10000.0f, -(float)(p + 1) / 64.0f);
    float s0, c0, s1, c1;
    sincosf((float)t * inv0, &s0, &c0);
    sincosf((float)t * inv1, &s1, &c1);
    uint2 o;
    o.x = pk2(kv.x * c0 - kv.y * s0, kv.x * s0 + kv.y * c0);
    o.y = pk2(kv.z * c1 - kv.w * s1, kv.z * s1 + kv.w * c1);
    *(uint2*)(krot + (size_t)row * DH + d) = o;
    return;
  }

  // ---- q projection: bf16 frag-major LDS tile, BK=128, 32-row tiles, fused RoPE ----
  int bid2 = bid - 2304;
  int wv = tid >> 6;
  int lane = tid & 63;
  int l15 = lane & 15;
  int quad = lane >> 4;
  int m0 = bid2 * 32;

  u16* Al = S;                           // [chunk16][row32][8], 8 KB

  int srow = tid >> 3;                   // 0..31
  int c16 = (tid & 7) * 16;              // col offset 0..112
  int chunk0 = (tid & 7) * 2;
  const float* xg = x + (size_t)(m0 + srow) * CDIM + c16;

  f32x4 acc[2][2];
#pragma unroll
  for (int mt = 0; mt < 2; ++mt)
#pragma unroll
    for (int nt = 0; nt < 2; ++nt) acc[mt][nt] = (f32x4){0.f, 0.f, 0.f, 0.f};

  float4 paA[4], paB[4];
#pragma unroll
  for (int i = 0; i < 4; ++i) paA[i] = *(const float4*)(xg + i * 4);
#pragma unroll
  for (int i = 0; i < 4; ++i) paB[i] = *(const float4*)(xg + 128 + i * 4);

  auto qstep = [&](float4 (&pa)[4], int itc) {
    u16x8 lo = cvt8u(pa[0], pa[1]);
    u16x8 hi = cvt8u(pa[2], pa[3]);
    if (itc + 2 < CDIM / 128) {
      const float* xn = xg + (size_t)(itc + 2) * 128;
#pragma unroll
      for (int i = 0; i < 4; ++i) pa[i] = *(const float4*)(xn + i * 4);
    }
    lds_barrier();
    *(u16x8*)&Al[(chunk0 * 32 + srow) * 8] = lo;
    *(u16x8*)&Al[((chunk0 + 1) * 32 + srow) * 8] = hi;
    lds_barrier();
    int k0 = itc * 128;
#pragma unroll
    for (int ks = 0; ks < 4; ++ks) {
      bf16x8 af[2];
#pragma unroll
      for (int mt = 0; mt < 2; ++mt)
        af[mt] = ld_bf8(&Al[(((ks * 4 + quad) * 32) + mt * 16 + l15) * 8]);
#pragma unroll
      for (int nt = 0; nt < 2; ++nt) {
        const float* wp = w + (size_t)(wv * 32 + nt * 16 + l15) * CDIM + k0 + ks * 32 + quad * 8;
        float4 w0 = *(const float4*)wp;
        float4 w1 = *(const float4*)(wp + 4);
        bf16x8 bfrag = __builtin_bit_cast(bf16x8, cvt8u(w0, w1));
#pragma unroll
        for (int mt = 0; mt < 2; ++mt)
          acc[mt][nt] = __builtin_amdgcn_mfma_f32_16x16x32_bf16(af[mt], bfrag, acc[mt][nt], 0, 0, 0);
      }
    }
  };

#pragma unroll 1
  for (int ith = 0; ith < 8; ++ith) {
    qstep(paA, 2 * ith);
    qstep(paB, 2 * ith + 1);
  }

  const float scale = 0.08838834764831845f;  // 128^-0.5
#pragma unroll
  for (int nt = 0; nt < 2; ++nt) {
    int dcol = wv * 32 + nt * 16 + l15;
    int p = dcol >> 1;
    float inv = powf(10000.0f, -(float)p / 64.0f);
#pragma unroll
    for (int mt = 0; mt < 2; ++mt) {
#pragma unroll
      for (int r = 0; r < 4; ++r) {
        int m = m0 + mt * 16 + quad * 4 + r;
        int t = m & (TSEQ - 1);
        float ang = (float)t * inv;
        float s, c; sincosf(ang, &s, &c);
        float val = acc[mt][nt][r];
        float partner = __shfl_xor(val, 1, 64);
        float o = (lane & 1) ? (val * c + partner * s) : (val * c - partner * s);
        qrot[(size_t)m * DH + dcol] = f2bf(o * scale);
      }
    }
  }
}

// ------- causal flash attention + fused split-K merge -------
// units = (b, 128-row q-tile, <=8 k-tiles of 64 keys). Last-finishing unit of
// each (b,Q) group merges the group's partials (device-scope atomic + fences).
__global__ __launch_bounds__(256, 2) void k_attn(const u16* __restrict__ qrot,
                                                 const u16* __restrict__ krot,
                                                 const u16* __restrict__ vt,
                                                 u16* __restrict__ Opart,
                                                 float2* __restrict__ ml,
                                                 int* __restrict__ cnt,
                                                 float* __restrict__ out) {
  __shared__ u16 Kl[16 * 64 * 8];
  __shared__ u16 Vl[8 * 128 * 8];
  __shared__ u16 Pl[4 * 32 * 72];
  __shared__ int s_last;

  int bid = blockIdx.x;                // 576 = 4 * 144
  int b = bid / 144;
  int u = bid - b * 144;
  int Q = 0;
#pragma unroll 1
  for (int q = 31; q >= 0; --q) {
    if (unit_base(q) <= u) { Q = q; break; }
  }
  int kc = u - unit_base(Q);
  int nkt = 2 * Q + 2;
  int kt0 = kc * 8;
  int kt1 = min(kt0 + 8, nkt);
  int m0 = Q * 128;
  int C = (Q >> 2) + 1;                // chunks in this (b,Q) group

  int tid = threadIdx.x;
  int w = tid >> 6;
  int lane = tid & 63;
  int l15 = lane & 15;
  int quad = lane >> 4;
  u16* pw = Pl + w * 32 * 72;

  int rK = tid & 63;   int jgK = tid >> 6;
  int dV = tid & 127;  int hV = tid >> 7;

  const u16* kb = krot + (size_t)b * TSEQ * DH;
  const u16* vb = vt + (size_t)b * DH * TSEQ;

  bf16x8 qf[2][4];
#pragma unroll
  for (int mt = 0; mt < 2; ++mt) {
    const u16* qb = qrot + ((size_t)(b * TSEQ + m0 + mt * 64 + w * 16 + l15)) * DH + quad * 8;
#pragma unroll
    for (int c = 0; c < 4; ++c) qf[mt][c] = ld_bf8(qb + c * 32);
  }

  f32x4 o_acc[2][8];
#pragma unroll
  for (int mt = 0; mt < 2; ++mt)
#pragma unroll
    for (int i = 0; i < 8; ++i) o_acc[mt][i] = (f32x4){0.f, 0.f, 0.f, 0.f};
  float m_st[2][4], l_st[2][4];
#pragma unroll
  for (int mt = 0; mt < 2; ++mt)
#pragma unroll
    for (int r = 0; r < 4; ++r) { m_st[mt][r] = -INFINITY; l_st[mt][r] = 0.f; }

  u16x8 kr[4], vr[4];
  {
    const u16* ks = kb + (size_t)(kt0 * 64 + rK) * DH + jgK * 32;
    const u16* vs = vb + (size_t)dV * TSEQ + kt0 * 64 + hV * 32;
#pragma unroll
    for (int i = 0; i < 4; ++i) { kr[i] = *(const u16x8*)(ks + i * 8); vr[i] = *(const u16x8*)(vs + i * 8); }
  }

  for (int kt = kt0; kt < kt1; ++kt) {
    lds_barrier();
#pragma unroll
    for (int i = 0; i < 4; ++i) {
      *(u16x8*)&Kl[((jgK * 4 + i) * 64 + rK) * 8] = kr[i];
      *(u16x8*)&Vl[((hV * 4 + i) * 128 + dV) * 8] = vr[i];
    }
    lds_barrier();
    if (kt + 1 < kt1) {
      const u16* ks = kb + (size_t)((kt + 1) * 64 + rK) * DH + jgK * 32;
      const u16* vs = vb + (size_t)dV * TSEQ + (kt + 1) * 64 + hV * 32;
#pragma unroll
      for (int i = 0; i < 4; ++i) { kr[i] = *(const u16x8*)(ks + i * 8); vr[i] = *(const u16x8*)(vs + i * 8); }
    }

    f32x4 s[2][4];
#pragma unroll
    for (int mt = 0; mt < 2; ++mt)
#pragma unroll
      for (int nt = 0; nt < 4; ++nt) s[mt][nt] = (f32x4){0.f, 0.f, 0.f, 0.f};
    __builtin_amdgcn_s_setprio(1);
#pragma unroll
    for (int c = 0; c < 4; ++c)
#pragma unroll
      for (int nt = 0; nt < 4; ++nt) {
        bf16x8 kf = ld_bf8(&Kl[((c * 4 + quad) * 64 + nt * 16 + l15) * 8]);
#pragma unroll
        for (int mt = 0; mt < 2; ++mt)
          s[mt][nt] = __builtin_amdgcn_mfma_f32_16x16x32_bf16(qf[mt][c], kf, s[mt][nt], 0, 0, 0);
      }
    __builtin_amdgcn_s_setprio(0);

    if (kt * 64 >= m0) {
#pragma unroll
      for (int mt = 0; mt < 2; ++mt)
#pragma unroll
        for (int nt = 0; nt < 4; ++nt)
#pragma unroll
          for (int r = 0; r < 4; ++r) {
            int key_g = kt * 64 + nt * 16 + l15;
            int row_g = m0 + mt * 64 + w * 16 + quad * 4 + r;
            if (key_g > row_g) s[mt][nt][r] = -INFINITY;
          }
    }

    float alpha[2][4];
    int chg = 0;
#pragma unroll
    for (int mt = 0; mt < 2; ++mt)
#pragma unroll
      for (int r = 0; r < 4; ++r) {
        float rm = fmaxf(fmaxf(s[mt][0][r], s[mt][1][r]), fmaxf(s[mt][2][r], s[mt][3][r]));
        rm = red_max16(rm);
        float mn = fmaxf(m_st[mt][r], rm);
        float al = __expf(m_st[mt][r] - mn);
        m_st[mt][r] = mn;
        float ps = 0.f;
#pragma unroll
        for (int nt = 0; nt < 4; ++nt) {
          float pv = __expf(s[mt][nt][r] - mn);
          s[mt][nt][r] = pv;
          ps += pv;
        }
        ps = red_sum16(ps);
        l_st[mt][r] = l_st[mt][r] * al + ps;
        alpha[mt][r] = al;
        chg |= (al != 1.0f);
      }
    if (__any(chg)) {
#pragma unroll
      for (int mt = 0; mt < 2; ++mt)
#pragma unroll
        for (int nt = 0; nt < 8; ++nt)
#pragma unroll
          for (int r = 0; r < 4; ++r) o_acc[mt][nt][r] *= alpha[mt][r];
    }

#pragma unroll
    for (int mt = 0; mt < 2; ++mt)
#pragma unroll
      for (int nt = 0; nt < 4; ++nt)
#pragma unroll
        for (int r = 0; r < 4; ++r)
          pw[(mt * 16 + quad * 4 + r) * 72 + nt * 16 + l15] = f2bf(s[mt][nt][r]);

#pragma unroll
    for (int c2 = 0; c2 < 2; ++c2) {
      bf16x8 pf[2];
#pragma unroll
      for (int mt = 0; mt < 2; ++mt)
        pf[mt] = ld_bf8(pw + (mt * 16 + l15) * 72 + c2 * 32 + quad * 8);
      __builtin_amdgcn_s_setprio(1);
#pragma unroll
      for (int nt = 0; nt < 8; ++nt) {
        bf16x8 vf = ld_bf8(&Vl[((c2 * 4 + quad) * 128 + nt * 16 + l15) * 8]);
#pragma unroll
        for (int mt = 0; mt < 2; ++mt)
          o_acc[mt][nt] = __builtin_amdgcn_mfma_f32_16x16x32_bf16(pf[mt], vf, o_acc[mt][nt], 0, 0, 0);
      }
      __builtin_amdgcn_s_setprio(0);
    }
  }

  if (C == 1) {
    // single-chunk group: write output directly (bf16 round-trip kept so the
    // result is bit-identical to the old Opart->merge path).
#pragma unroll
    for (int mt = 0; mt < 2; ++mt)
#pragma unroll
      for (int r = 0; r < 4; ++r) {
        float invl = 1.f / l_st[mt][r];
        int row = m0 + mt * 64 + w * 16 + quad * 4 + r;
        float* op = out + ((size_t)(b * TSEQ + row)) * DH;
#pragma unroll
        for (int nt = 0; nt < 8; ++nt)
          op[nt * 16 + l15] = bf2f(f2bf(o_acc[mt][nt][r])) * invl;
      }
    return;
  }

  u16* op = Opart + (size_t)bid * (128 * 128);
#pragma unroll
  for (int mt = 0; mt < 2; ++mt)
#pragma unroll
    for (int nt = 0; nt < 8; ++nt)
#pragma unroll
      for (int r = 0; r < 4; ++r)
        op[(mt * 64 + w * 16 + quad * 4 + r) * 128 + nt * 16 + l15] = f2bf(o_acc[mt][nt][r]);
  if (l15 == 0) {
#pragma unroll
    for (int mt = 0; mt < 2; ++mt)
#pragma unroll
      for (int r = 0; r < 4; ++r) {
        float2 p; p.x = m_st[mt][r]; p.y = l_st[mt][r];
        ml[(size_t)bid * 128 + mt * 64 + w * 16 + quad * 4 + r] = p;
      }
  }

  // ---- last-arriving chunk of this (b,Q) group merges the partials ----
  __threadfence();                      // release: Opart/ml visible device-wide
  if (tid == 0) s_last = (atomicAdd(&cnt[b * 32 + Q], 1) == C - 1);
  __syncthreads();
  if (!s_last) return;
  __threadfence();                      // acquire: see other chunks' writes

  int base = b * 144 + unit_base(Q);
  float* wgt = (float*)Kl;             // overlay: 8*128 + 128 floats = 4.6 KB
  float* invL = wgt + 8 * 128;
  if (tid < 128) {
    float mv[8], lv[8];
    float M = -INFINITY;
#pragma unroll
    for (int c = 0; c < 8; ++c)
      if (c < C) {
        float2 p = ml[(size_t)(base + c) * 128 + tid];
        mv[c] = p.x; lv[c] = p.y;
        M = fmaxf(M, p.x);
      }
    float L = 0.f;
#pragma unroll
    for (int c = 0; c < 8; ++c)
      if (c < C) {
        float wvv = __expf(mv[c] - M);
        wgt[c * 128 + tid] = wvv;
        L += wvv * lv[c];
      }
    invL[tid] = 1.f / L;
  }
  __syncthreads();
#pragma unroll
  for (int k = 0; k < 8; ++k) {
    int slot = tid + k * 256;          // 2048 slots of 8 elems (128x128)
    int row = slot >> 4;
    float acc[8];
#pragma unroll
    for (int j = 0; j < 8; ++j) acc[j] = 0.f;
    for (int c = 0; c < C; ++c) {
      u16x8 v = *(const u16x8*)&Opart[(size_t)(base + c) * (128 * 128) + slot * 8];
      float wvv = wgt[c * 128 + row];
#pragma unroll
      for (int j = 0; j < 8; ++j) acc[j] += wvv * bf2f(v[j]);
    }
    float il = invL[row];
    float4 o0, o1;
    o0.x = acc[0] * il; o0.y = acc[1] * il; o0.z = acc[2] * il; o0.w = acc[3] * il;
    o1.x = acc[4] * il; o1.y = acc[5] * il; o1.z = acc[6] * il; o1.w = acc[7] * il;
    float* opt = out + ((size_t)(b * TSEQ + Q * 128 + row)) * DH + (slot & 15) * 8;
    *(float4*)opt = o0;
    *(float4*)(opt + 4) = o1;
  }
}

extern "C" void kernel_launch(void* const* d_in, const int* in_sizes, int n_in,
                              void* d_out, int out_size, void* d_ws, size_t ws_size,
                              hipStream_t stream) {
  const float* x     = (const float*)d_in[0];
  const float* key   = (const float*)d_in[1];
  const float* value = (const float*)d_in[2];
  const float* w_q   = (const float*)d_in[3];
  float* out = (float*)d_out;

  char* ws = (char*)d_ws;
  u16* qrot   = (u16*)(ws);                    // 4 MB
  u16* krot   = (u16*)(ws + (4u  << 20));      // 4 MB
  u16* vt     = (u16*)(ws + (8u  << 20));      // 4 MB
  u16* Opart  = (u16*)(ws + (12u << 20));      // 18.87 MB
  float2* ml  = (float2*)(ws + (31u << 20));   // 590 KB
  int* cnt    = (int*)(ws + (32u << 20));      // 512 B

  // grid: 256 vt + 2048 ropek + 512 qproj
  k_fused1<<<2816, 256, 0, stream>>>(w_q, key, krot, value, vt, x, qrot, cnt);
  k_attn<<<NBATCH * 144, 256, 0, stream>>>(qrot, krot, vt, Opart, ml, cnt, out);
}

// Round 3
// 348.190 us; speedup vs baseline: 1.2788x; 1.2788x over previous
//
#include <hip/hip_runtime.h>
#include <hip/hip_bf16.h>

#define TSEQ  4096
#define NBATCH 4
#define CDIM  2048
#define DH    128

typedef __bf16 bf16x8 __attribute__((ext_vector_type(8)));
typedef float  f32x4  __attribute__((ext_vector_type(4)));
typedef unsigned short u16x8 __attribute__((ext_vector_type(8)));
typedef unsigned       u32x4 __attribute__((ext_vector_type(4)));
typedef unsigned short u16;

__device__ __forceinline__ u16 f2bf(float f) {
  union { float f; unsigned u; } v; v.f = f;
  unsigned r = (v.u + 0x7FFFu + ((v.u >> 16) & 1u)) >> 16;
  return (u16)r;
}
__device__ __forceinline__ float bf2f(u16 h) {
  union { unsigned u; float f; } v; v.u = ((unsigned)h) << 16;
  return v.f;
}
__device__ __forceinline__ bf16x8 ld_bf8(const u16* p) {
  return __builtin_bit_cast(bf16x8, *(const u16x8*)p);
}
__device__ __forceinline__ unsigned pk2(float lo, float hi) {
  float2 f; f.x = lo; f.y = hi;
  __hip_bfloat162 h = __float22bfloat162_rn(f);
  unsigned r; __builtin_memcpy(&r, &h, 4);
  return r;
}
__device__ __forceinline__ u16x8 cvt8u(float4 a, float4 b) {
  u32x4 u;
  u[0] = pk2(a.x, a.y); u[1] = pk2(a.z, a.w);
  u[2] = pk2(b.x, b.y); u[3] = pk2(b.z, b.w);
  return __builtin_bit_cast(u16x8, u);
}

// raw workgroup barrier: drains LDS (lgkmcnt) only, NOT vmcnt — keeps global
// prefetch loads in flight across the barrier.
__device__ __forceinline__ void lds_barrier() {
  asm volatile("s_waitcnt lgkmcnt(0)" ::: "memory");
  __builtin_amdgcn_s_barrier();
}

// DPP cross-lane (VALU pipe): reduce over each 16-lane row
template<int CTRL>
__device__ __forceinline__ float dppmv(float x) {
  return __builtin_bit_cast(float,
    __builtin_amdgcn_update_dpp(0, __builtin_bit_cast(int, x), CTRL, 0xF, 0xF, true));
}
__device__ __forceinline__ float red_max16(float v) {
  v = fmaxf(v, dppmv<0xB1>(v));
  v = fmaxf(v, dppmv<0x4E>(v));
  v = fmaxf(v, dppmv<0x124>(v));
  v = fmaxf(v, dppmv<0x128>(v));
  return v;
}
__device__ __forceinline__ float red_sum16(float v) {
  v += dppmv<0xB1>(v);
  v += dppmv<0x4E>(v);
  v += dppmv<0x124>(v);
  v += dppmv<0x128>(v);
  return v;
}

// unit base within a batch: q-tile Q (128 rows) has (Q>>2)+1 chunks
__device__ __forceinline__ int unit_base(int Q) {
  int a = Q >> 2, bq = Q & 3;
  return 2 * a * (a + 1) + bq * (a + 1);
}

// ---------------- fused kernel 1: vt | ropek | qproj ----------------
// qproj reads w_q fp32 directly (in-register bf16 cvt, bit-identical to the
// old wbf path) -> no dependency on prep outputs -> single launch.
__global__ __launch_bounds__(256, 2) void k_fused1(const float* __restrict__ w,
                                                   const float* __restrict__ key,
                                                   u16* __restrict__ krot,
                                                   const float* __restrict__ value,
                                                   u16* __restrict__ vt,
                                                   const float* __restrict__ x,
                                                   u16* __restrict__ qrot) {
  __shared__ u16 S[128 * 66];            // vt transpose tile; qproj reuses 8 KB of it
  int bid = blockIdx.x;
  int tid = threadIdx.x;

  if (bid < 256) {
    // ---- value transpose [B,T,D] -> [B,D,T] in bf16 ----
    int b = bid >> 6;
    int t0 = (bid & 63) * 64;
    int d = (tid & 31) * 4;
    int tl0 = tid >> 5;
#pragma unroll
    for (int i = 0; i < 8; ++i) {
      int tl = tl0 + i * 8;
      const float4 val = *(const float4*)(value + ((size_t)(b * TSEQ + t0 + tl)) * DH + d);
      S[(d + 0) * 66 + tl] = f2bf(val.x);
      S[(d + 1) * 66 + tl] = f2bf(val.y);
      S[(d + 2) * 66 + tl] = f2bf(val.z);
      S[(d + 3) * 66 + tl] = f2bf(val.w);
    }
    __syncthreads();
#pragma unroll
    for (int i = 0; i < 16; ++i) {
      int idx = tid + i * 256;
      int dd = idx >> 5;
      int tw = (idx & 31) * 2;
      unsigned lo = S[dd * 66 + tw];
      unsigned hi = S[dd * 66 + tw + 1];
      *(unsigned*)(vt + ((size_t)(b * DH + dd)) * TSEQ + t0 + tw) = lo | (hi << 16);
    }
    return;
  }

  if (bid < 2304) {
    // ---- RoPE on key, 16 B/thread (2 pairs), fp32 -> bf16 ----
    int idx = (bid - 256) * 256 + tid;   // float4 index
    int f0 = idx * 4;
    int row = f0 >> 7;                   // /DH (floats per row)
    int d = f0 & 127;
    int p = d >> 1;                      // even pair index; handles p and p+1
    int t = row & (TSEQ - 1);
    const float4 kv = *(const float4*)(key + (size_t)row * DH + d);
    float inv0 = powf(10000.0f, -(float)p / 64.0f);
    float inv1 = powf(10000.0f, -(float)(p + 1) / 64.0f);
    float s0, c0, s1, c1;
    sincosf((float)t * inv0, &s0, &c0);
    sincosf((float)t * inv1, &s1, &c1);
    uint2 o;
    o.x = pk2(kv.x * c0 - kv.y * s0, kv.x * s0 + kv.y * c0);
    o.y = pk2(kv.z * c1 - kv.w * s1, kv.z * s1 + kv.w * c1);
    *(uint2*)(krot + (size_t)row * DH + d) = o;
    return;
  }

  // ---- q projection: bf16 frag-major LDS tile, BK=128, 32-row tiles, fused RoPE ----
  int bid2 = bid - 2304;
  int wv = tid >> 6;
  int lane = tid & 63;
  int l15 = lane & 15;
  int quad = lane >> 4;
  int m0 = bid2 * 32;

  u16* Al = S;                           // [chunk16][row32][8], 8 KB

  int srow = tid >> 3;                   // 0..31
  int c16 = (tid & 7) * 16;              // col offset 0..112
  int chunk0 = (tid & 7) * 2;
  const float* xg = x + (size_t)(m0 + srow) * CDIM + c16;

  f32x4 acc[2][2];
#pragma unroll
  for (int mt = 0; mt < 2; ++mt)
#pragma unroll
    for (int nt = 0; nt < 2; ++nt) acc[mt][nt] = (f32x4){0.f, 0.f, 0.f, 0.f};

  float4 paA[4], paB[4];
#pragma unroll
  for (int i = 0; i < 4; ++i) paA[i] = *(const float4*)(xg + i * 4);
#pragma unroll
  for (int i = 0; i < 4; ++i) paB[i] = *(const float4*)(xg + 128 + i * 4);

  auto qstep = [&](float4 (&pa)[4], int itc) {
    u16x8 lo = cvt8u(pa[0], pa[1]);
    u16x8 hi = cvt8u(pa[2], pa[3]);
    if (itc + 2 < CDIM / 128) {
      const float* xn = xg + (size_t)(itc + 2) * 128;
#pragma unroll
      for (int i = 0; i < 4; ++i) pa[i] = *(const float4*)(xn + i * 4);
    }
    lds_barrier();
    *(u16x8*)&Al[(chunk0 * 32 + srow) * 8] = lo;
    *(u16x8*)&Al[((chunk0 + 1) * 32 + srow) * 8] = hi;
    lds_barrier();
    int k0 = itc * 128;
#pragma unroll
    for (int ks = 0; ks < 4; ++ks) {
      bf16x8 af[2];
#pragma unroll
      for (int mt = 0; mt < 2; ++mt)
        af[mt] = ld_bf8(&Al[(((ks * 4 + quad) * 32) + mt * 16 + l15) * 8]);
#pragma unroll
      for (int nt = 0; nt < 2; ++nt) {
        const float* wp = w + (size_t)(wv * 32 + nt * 16 + l15) * CDIM + k0 + ks * 32 + quad * 8;
        float4 w0 = *(const float4*)wp;
        float4 w1 = *(const float4*)(wp + 4);
        bf16x8 bfrag = __builtin_bit_cast(bf16x8, cvt8u(w0, w1));
#pragma unroll
        for (int mt = 0; mt < 2; ++mt)
          acc[mt][nt] = __builtin_amdgcn_mfma_f32_16x16x32_bf16(af[mt], bfrag, acc[mt][nt], 0, 0, 0);
      }
    }
  };

#pragma unroll 1
  for (int ith = 0; ith < 8; ++ith) {
    qstep(paA, 2 * ith);
    qstep(paB, 2 * ith + 1);
  }

  const float scale = 0.08838834764831845f;  // 128^-0.5
#pragma unroll
  for (int nt = 0; nt < 2; ++nt) {
    int dcol = wv * 32 + nt * 16 + l15;
    int p = dcol >> 1;
    float inv = powf(10000.0f, -(float)p / 64.0f);
#pragma unroll
    for (int mt = 0; mt < 2; ++mt) {
#pragma unroll
      for (int r = 0; r < 4; ++r) {
        int m = m0 + mt * 16 + quad * 4 + r;
        int t = m & (TSEQ - 1);
        float ang = (float)t * inv;
        float s, c; sincosf(ang, &s, &c);
        float val = acc[mt][nt][r];
        float partner = __shfl_xor(val, 1, 64);
        float o = (lane & 1) ? (val * c + partner * s) : (val * c - partner * s);
        qrot[(size_t)m * DH + dcol] = f2bf(o * scale);
      }
    }
  }
}

// ------- causal flash attention: units = (b, 128-row q-tile, <=8 k-tiles of 64 keys) -------
// Dispatch order reversed within each batch (largest/high-Q units first) so the
// 64 blocks of the second scheduling wave are the SMALLEST units (LJF). Opart/ml
// are indexed by the LOGICAL unit id, so k_merge is unchanged.
__global__ __launch_bounds__(256, 2) void k_attn(const u16* __restrict__ qrot,
                                                 const u16* __restrict__ krot,
                                                 const u16* __restrict__ vt,
                                                 u16* __restrict__ Opart,
                                                 float2* __restrict__ ml) {
  __shared__ u16 Kl[16 * 64 * 8];
  __shared__ u16 Vl[8 * 128 * 8];
  __shared__ u16 Pl[4 * 32 * 72];

  int bid = blockIdx.x;                // 576 = 4 * 144
  int b = bid / 144;
  int u = 143 - (bid - b * 144);       // big-Q (longest) units dispatch first
  int uid = b * 144 + u;               // logical unit id for Opart/ml
  int Q = 0;
#pragma unroll 1
  for (int q = 31; q >= 0; --q) {
    if (unit_base(q) <= u) { Q = q; break; }
  }
  int kc = u - unit_base(Q);
  int nkt = 2 * Q + 2;
  int kt0 = kc * 8;
  int kt1 = min(kt0 + 8, nkt);
  int m0 = Q * 128;

  int tid = threadIdx.x;
  int w = tid >> 6;
  int lane = tid & 63;
  int l15 = lane & 15;
  int quad = lane >> 4;
  u16* pw = Pl + w * 32 * 72;

  int rK = tid & 63;   int jgK = tid >> 6;
  int dV = tid & 127;  int hV = tid >> 7;

  const u16* kb = krot + (size_t)b * TSEQ * DH;
  const u16* vb = vt + (size_t)b * DH * TSEQ;

  bf16x8 qf[2][4];
#pragma unroll
  for (int mt = 0; mt < 2; ++mt) {
    const u16* qb = qrot + ((size_t)(b * TSEQ + m0 + mt * 64 + w * 16 + l15)) * DH + quad * 8;
#pragma unroll
    for (int c = 0; c < 4; ++c) qf[mt][c] = ld_bf8(qb + c * 32);
  }

  f32x4 o_acc[2][8];
#pragma unroll
  for (int mt = 0; mt < 2; ++mt)
#pragma unroll
    for (int i = 0; i < 8; ++i) o_acc[mt][i] = (f32x4){0.f, 0.f, 0.f, 0.f};
  float m_st[2][4], l_st[2][4];
#pragma unroll
  for (int mt = 0; mt < 2; ++mt)
#pragma unroll
    for (int r = 0; r < 4; ++r) { m_st[mt][r] = -INFINITY; l_st[mt][r] = 0.f; }

  u16x8 kr[4], vr[4];
  {
    const u16* ks = kb + (size_t)(kt0 * 64 + rK) * DH + jgK * 32;
    const u16* vs = vb + (size_t)dV * TSEQ + kt0 * 64 + hV * 32;
#pragma unroll
    for (int i = 0; i < 4; ++i) { kr[i] = *(const u16x8*)(ks + i * 8); vr[i] = *(const u16x8*)(vs + i * 8); }
  }

  for (int kt = kt0; kt < kt1; ++kt) {
    lds_barrier();
#pragma unroll
    for (int i = 0; i < 4; ++i) {
      *(u16x8*)&Kl[((jgK * 4 + i) * 64 + rK) * 8] = kr[i];
      *(u16x8*)&Vl[((hV * 4 + i) * 128 + dV) * 8] = vr[i];
    }
    lds_barrier();
    if (kt + 1 < kt1) {
      const u16* ks = kb + (size_t)((kt + 1) * 64 + rK) * DH + jgK * 32;
      const u16* vs = vb + (size_t)dV * TSEQ + (kt + 1) * 64 + hV * 32;
#pragma unroll
      for (int i = 0; i < 4; ++i) { kr[i] = *(const u16x8*)(ks + i * 8); vr[i] = *(const u16x8*)(vs + i * 8); }
    }

    f32x4 s[2][4];
#pragma unroll
    for (int mt = 0; mt < 2; ++mt)
#pragma unroll
      for (int nt = 0; nt < 4; ++nt) s[mt][nt] = (f32x4){0.f, 0.f, 0.f, 0.f};
    __builtin_amdgcn_s_setprio(1);
#pragma unroll
    for (int c = 0; c < 4; ++c)
#pragma unroll
      for (int nt = 0; nt < 4; ++nt) {
        bf16x8 kf = ld_bf8(&Kl[((c * 4 + quad) * 64 + nt * 16 + l15) * 8]);
#pragma unroll
        for (int mt = 0; mt < 2; ++mt)
          s[mt][nt] = __builtin_amdgcn_mfma_f32_16x16x32_bf16(qf[mt][c], kf, s[mt][nt], 0, 0, 0);
      }
    __builtin_amdgcn_s_setprio(0);

    if (kt * 64 >= m0) {
#pragma unroll
      for (int mt = 0; mt < 2; ++mt)
#pragma unroll
        for (int nt = 0; nt < 4; ++nt)
#pragma unroll
          for (int r = 0; r < 4; ++r) {
            int key_g = kt * 64 + nt * 16 + l15;
            int row_g = m0 + mt * 64 + w * 16 + quad * 4 + r;
            if (key_g > row_g) s[mt][nt][r] = -INFINITY;
          }
    }

    float alpha[2][4];
    int chg = 0;
#pragma unroll
    for (int mt = 0; mt < 2; ++mt)
#pragma unroll
      for (int r = 0; r < 4; ++r) {
        float rm = fmaxf(fmaxf(s[mt][0][r], s[mt][1][r]), fmaxf(s[mt][2][r], s[mt][3][r]));
        rm = red_max16(rm);
        float mn = fmaxf(m_st[mt][r], rm);
        float al = __expf(m_st[mt][r] - mn);
        m_st[mt][r] = mn;
        float ps = 0.f;
#pragma unroll
        for (int nt = 0; nt < 4; ++nt) {
          float pv = __expf(s[mt][nt][r] - mn);
          s[mt][nt][r] = pv;
          ps += pv;
        }
        ps = red_sum16(ps);
        l_st[mt][r] = l_st[mt][r] * al + ps;
        alpha[mt][r] = al;
        chg |= (al != 1.0f);
      }
    if (__any(chg)) {
#pragma unroll
      for (int mt = 0; mt < 2; ++mt)
#pragma unroll
        for (int nt = 0; nt < 8; ++nt)
#pragma unroll
          for (int r = 0; r < 4; ++r) o_acc[mt][nt][r] *= alpha[mt][r];
    }

#pragma unroll
    for (int mt = 0; mt < 2; ++mt)
#pragma unroll
      for (int nt = 0; nt < 4; ++nt)
#pragma unroll
        for (int r = 0; r < 4; ++r)
          pw[(mt * 16 + quad * 4 + r) * 72 + nt * 16 + l15] = f2bf(s[mt][nt][r]);

#pragma unroll
    for (int c2 = 0; c2 < 2; ++c2) {
      bf16x8 pf[2];
#pragma unroll
      for (int mt = 0; mt < 2; ++mt)
        pf[mt] = ld_bf8(pw + (mt * 16 + l15) * 72 + c2 * 32 + quad * 8);
      __builtin_amdgcn_s_setprio(1);
#pragma unroll
      for (int nt = 0; nt < 8; ++nt) {
        bf16x8 vf = ld_bf8(&Vl[((c2 * 4 + quad) * 128 + nt * 16 + l15) * 8]);
#pragma unroll
        for (int mt = 0; mt < 2; ++mt)
          o_acc[mt][nt] = __builtin_amdgcn_mfma_f32_16x16x32_bf16(pf[mt], vf, o_acc[mt][nt], 0, 0, 0);
      }
      __builtin_amdgcn_s_setprio(0);
    }
  }

  u16* op = Opart + (size_t)uid * (128 * 128);
#pragma unroll
  for (int mt = 0; mt < 2; ++mt)
#pragma unroll
    for (int nt = 0; nt < 8; ++nt)
#pragma unroll
      for (int r = 0; r < 4; ++r)
        op[(mt * 64 + w * 16 + quad * 4 + r) * 128 + nt * 16 + l15] = f2bf(o_acc[mt][nt][r]);
  if (l15 == 0) {
#pragma unroll
    for (int mt = 0; mt < 2; ++mt)
#pragma unroll
      for (int r = 0; r < 4; ++r) {
        float2 p; p.x = m_st[mt][r]; p.y = l_st[mt][r];
        ml[(size_t)uid * 128 + mt * 64 + w * 16 + quad * 4 + r] = p;
      }
  }
}

// ------- merge partials: one block per (b, 128-row q-tile), vectorized -------
__global__ __launch_bounds__(256) void k_merge(const u16* __restrict__ Opart,
                                               const float2* __restrict__ ml,
                                               float* __restrict__ out) {
  __shared__ float wgt[8][128];
  __shared__ float invL[128];
  int bid = blockIdx.x;                // b*32 + Q
  int b = bid >> 5, Q = bid & 31;
  int C = (Q >> 2) + 1;
  int base = b * 144 + unit_base(Q);
  int tid = threadIdx.x;
  if (tid < 128) {
    float mv[8], lv[8];
    float M = -INFINITY;
    for (int c = 0; c < C; ++c) {
      float2 p = ml[(size_t)(base + c) * 128 + tid];
      mv[c] = p.x; lv[c] = p.y;
      M = fmaxf(M, p.x);
    }
    float L = 0.f;
    for (int c = 0; c < C; ++c) {
      float wv = __expf(mv[c] - M);
      wgt[c][tid] = wv;
      L += wv * lv[c];
    }
    invL[tid] = 1.f / L;
  }
  __syncthreads();
#pragma unroll
  for (int k = 0; k < 8; ++k) {
    int slot = tid + k * 256;          // 2048 slots of 8 elems (128x128)
    int row = slot >> 4;
    float acc[8];
#pragma unroll
    for (int j = 0; j < 8; ++j) acc[j] = 0.f;
    for (int c = 0; c < C; ++c) {
      u16x8 v = *(const u16x8*)&Opart[(size_t)(base + c) * (128 * 128) + slot * 8];
      float wv = wgt[c][row];
#pragma unroll
      for (int j = 0; j < 8; ++j) acc[j] += wv * bf2f(v[j]);
    }
    float il = invL[row];
    float4 o0, o1;
    o0.x = acc[0] * il; o0.y = acc[1] * il; o0.z = acc[2] * il; o0.w = acc[3] * il;
    o1.x = acc[4] * il; o1.y = acc[5] * il; o1.z = acc[6] * il; o1.w = acc[7] * il;
    float* op = out + ((size_t)(b * TSEQ + Q * 128 + row)) * DH + (slot & 15) * 8;
    *(float4*)op = o0;
    *(float4*)(op + 4) = o1;
  }
}

extern "C" void kernel_launch(void* const* d_in, const int* in_sizes, int n_in,
                              void* d_out, int out_size, void* d_ws, size_t ws_size,
                              hipStream_t stream) {
  const float* x     = (const float*)d_in[0];
  const float* key   = (const float*)d_in[1];
  const float* value = (const float*)d_in[2];
  const float* w_q   = (const float*)d_in[3];
  float* out = (float*)d_out;

  char* ws = (char*)d_ws;
  u16* qrot   = (u16*)(ws);                    // 4 MB
  u16* krot   = (u16*)(ws + (4u  << 20));      // 4 MB
  u16* vt     = (u16*)(ws + (8u  << 20));      // 4 MB
  u16* Opart  = (u16*)(ws + (12u << 20));      // 18.87 MB
  float2* ml  = (float2*)(ws + (31u << 20));   // 590 KB

  // grid: 256 vt + 2048 ropek + 512 qproj
  k_fused1<<<2816, 256, 0, stream>>>(w_q, key, krot, value, vt, x, qrot);
  k_attn<<<NBATCH * 144, 256, 0, stream>>>(qrot, krot, vt, Opart, ml);
  k_merge<<<NBATCH * 32, 256, 0, stream>>>(Opart, ml, out);
}

// Round 4
// 303.798 us; speedup vs baseline: 1.4657x; 1.1461x over previous
//
#include <hip/hip_runtime.h>
#include <hip/hip_bf16.h>

#define TSEQ  4096
#define NBATCH 4
#define CDIM  2048
#define DH    128

typedef __bf16 bf16x8 __attribute__((ext_vector_type(8)));
typedef float  f32x4  __attribute__((ext_vector_type(4)));
typedef unsigned short u16x8 __attribute__((ext_vector_type(8)));
typedef unsigned       u32x4 __attribute__((ext_vector_type(4)));
typedef unsigned short u16;

__device__ __forceinline__ u16 f2bf(float f) {
  union { float f; unsigned u; } v; v.f = f;
  unsigned r = (v.u + 0x7FFFu + ((v.u >> 16) & 1u)) >> 16;
  return (u16)r;
}
__device__ __forceinline__ float bf2f(u16 h) {
  union { unsigned u; float f; } v; v.u = ((unsigned)h) << 16;
  return v.f;
}
__device__ __forceinline__ bf16x8 ld_bf8(const u16* p) {
  return __builtin_bit_cast(bf16x8, *(const u16x8*)p);
}
__device__ __forceinline__ unsigned pk2(float lo, float hi) {
  float2 f; f.x = lo; f.y = hi;
  __hip_bfloat162 h = __float22bfloat162_rn(f);
  unsigned r; __builtin_memcpy(&r, &h, 4);
  return r;
}
__device__ __forceinline__ u16x8 cvt8u(float4 a, float4 b) {
  u32x4 u;
  u[0] = pk2(a.x, a.y); u[1] = pk2(a.z, a.w);
  u[2] = pk2(b.x, b.y); u[3] = pk2(b.z, b.w);
  return __builtin_bit_cast(u16x8, u);
}

// raw workgroup barrier: drains LDS (lgkmcnt) only, NOT vmcnt — keeps global
// prefetch loads in flight across the barrier.
__device__ __forceinline__ void lds_barrier() {
  asm volatile("s_waitcnt lgkmcnt(0)" ::: "memory");
  __builtin_amdgcn_s_barrier();
}

// DPP cross-lane (VALU pipe): reduce over each 16-lane row
template<int CTRL>
__device__ __forceinline__ float dppmv(float x) {
  return __builtin_bit_cast(float,
    __builtin_amdgcn_update_dpp(0, __builtin_bit_cast(int, x), CTRL, 0xF, 0xF, true));
}
__device__ __forceinline__ float red_max16(float v) {
  v = fmaxf(v, dppmv<0xB1>(v));
  v = fmaxf(v, dppmv<0x4E>(v));
  v = fmaxf(v, dppmv<0x124>(v));
  v = fmaxf(v, dppmv<0x128>(v));
  return v;
}
__device__ __forceinline__ float red_sum16(float v) {
  v += dppmv<0xB1>(v);
  v += dppmv<0x4E>(v);
  v += dppmv<0x124>(v);
  v += dppmv<0x128>(v);
  return v;
}

// unit base within a batch: q-tile Q (128 rows) has (Q>>2)+1 chunks
__device__ __forceinline__ int unit_base(int Q) {
  int a = Q >> 2, bq = Q & 3;
  return 2 * a * (a + 1) + bq * (a + 1);
}

// ---------------- w_q fp32 -> bf16 (tiny; separate launch for ordering) ----------------
__global__ __launch_bounds__(256) void k_wconv(const float* __restrict__ w, u16* __restrict__ wbf) {
  int i = blockIdx.x * 256 + threadIdx.x;
  const float4 v = *(const float4*)(w + (size_t)i * 4);
  uint2 o; o.x = pk2(v.x, v.y); o.y = pk2(v.z, v.w);
  *(uint2*)(wbf + (size_t)i * 4) = o;
}

// ---------------- fused kernel: vt | ropek | qproj ----------------
__global__ __launch_bounds__(256, 2) void k_fused1(const u16* __restrict__ wbf,
                                                   const float* __restrict__ key,
                                                   u16* __restrict__ krot,
                                                   const float* __restrict__ value,
                                                   u16* __restrict__ vt,
                                                   const float* __restrict__ x,
                                                   u16* __restrict__ qrot) {
  __shared__ u16 S[128 * 66];            // vt transpose tile; qproj reuses 8 KB of it
  int bid = blockIdx.x;
  int tid = threadIdx.x;

  if (bid < 256) {
    // ---- value transpose [B,T,D] -> [B,D,T] in bf16 ----
    int b = bid >> 6;
    int t0 = (bid & 63) * 64;
    int d = (tid & 31) * 4;
    int tl0 = tid >> 5;
#pragma unroll
    for (int i = 0; i < 8; ++i) {
      int tl = tl0 + i * 8;
      const float4 val = *(const float4*)(value + ((size_t)(b * TSEQ + t0 + tl)) * DH + d);
      S[(d + 0) * 66 + tl] = f2bf(val.x);
      S[(d + 1) * 66 + tl] = f2bf(val.y);
      S[(d + 2) * 66 + tl] = f2bf(val.z);
      S[(d + 3) * 66 + tl] = f2bf(val.w);
    }
    __syncthreads();
#pragma unroll
    for (int i = 0; i < 16; ++i) {
      int idx = tid + i * 256;
      int dd = idx >> 5;
      int tw = (idx & 31) * 2;
      unsigned lo = S[dd * 66 + tw];
      unsigned hi = S[dd * 66 + tw + 1];
      *(unsigned*)(vt + ((size_t)(b * DH + dd)) * TSEQ + t0 + tw) = lo | (hi << 16);
    }
    return;
  }

  if (bid < 2304) {
    // ---- RoPE on key, 16 B/thread (2 pairs), fp32 -> bf16 ----
    int idx = (bid - 256) * 256 + tid;   // float4 index
    int f0 = idx * 4;
    int row = f0 >> 7;                   // /DH (floats per row)
    int d = f0 & 127;
    int p = d >> 1;                      // even pair index; handles p and p+1
    int t = row & (TSEQ - 1);
    const float4 kv = *(const float4*)(key + (size_t)row * DH + d);
    float inv0 = powf(10000.0f, -(float)p / 64.0f);
    float inv1 = powf(10000.0f, -(float)(p + 1) / 64.0f);
    float s0, c0, s1, c1;
    sincosf((float)t * inv0, &s0, &c0);
    sincosf((float)t * inv1, &s1, &c1);
    uint2 o;
    o.x = pk2(kv.x * c0 - kv.y * s0, kv.x * s0 + kv.y * c0);
    o.y = pk2(kv.z * c1 - kv.w * s1, kv.z * s1 + kv.w * c1);
    *(uint2*)(krot + (size_t)row * DH + d) = o;
    return;
  }

  // ---- q projection: bf16 frag-major LDS tile, BK=128, 32-row tiles, fused RoPE ----
  // LDS physical row is swizzled: prow = (row + (chunk>>1)) & 31. This spreads the
  // staging writes (same srow, 8 different chunks per tid&7 group) across all 8
  // bank groups: 8-way write conflict -> none. Applied identically on read.
  int bid2 = bid - 2304;
  int wv = tid >> 6;
  int lane = tid & 63;
  int l15 = lane & 15;
  int quad = lane >> 4;
  int m0 = bid2 * 32;

  u16* Al = S;                           // [chunk16][prow32][8], 8 KB

  int srow = tid >> 3;                   // 0..31
  int c16 = (tid & 7) * 16;              // col offset 0..112
  int chunk0 = (tid & 7) * 2;
  int prow = (srow + (tid & 7)) & 31;    // (chunk0>>1) == ((chunk0+1)>>1) == tid&7
  const float* xg = x + (size_t)(m0 + srow) * CDIM + c16;

  f32x4 acc[2][2];
#pragma unroll
  for (int mt = 0; mt < 2; ++mt)
#pragma unroll
    for (int nt = 0; nt < 2; ++nt) acc[mt][nt] = (f32x4){0.f, 0.f, 0.f, 0.f};

  float4 paA[4], paB[4];
#pragma unroll
  for (int i = 0; i < 4; ++i) paA[i] = *(const float4*)(xg + i * 4);
#pragma unroll
  for (int i = 0; i < 4; ++i) paB[i] = *(const float4*)(xg + 128 + i * 4);

  auto qstep = [&](float4 (&pa)[4], int itc) {
    u16x8 lo = cvt8u(pa[0], pa[1]);
    u16x8 hi = cvt8u(pa[2], pa[3]);
    if (itc + 2 < CDIM / 128) {
      const float* xn = xg + (size_t)(itc + 2) * 128;
#pragma unroll
      for (int i = 0; i < 4; ++i) pa[i] = *(const float4*)(xn + i * 4);
    }
    lds_barrier();
    *(u16x8*)&Al[(chunk0 * 32 + prow) * 8] = lo;
    *(u16x8*)&Al[((chunk0 + 1) * 32 + prow) * 8] = hi;
    lds_barrier();
    int k0 = itc * 128;
#pragma unroll
    for (int ks = 0; ks < 4; ++ks) {
      bf16x8 af[2];
#pragma unroll
      for (int mt = 0; mt < 2; ++mt) {
        int rr = (mt * 16 + l15 + ks * 2 + (quad >> 1)) & 31;  // (chunk>>1) = ks*2 + (quad>>1)
        af[mt] = ld_bf8(&Al[(((ks * 4 + quad) * 32) + rr) * 8]);
      }
#pragma unroll
      for (int nt = 0; nt < 2; ++nt) {
        bf16x8 bfrag = ld_bf8(wbf + (size_t)(wv * 32 + nt * 16 + l15) * CDIM + k0 + ks * 32 + quad * 8);
#pragma unroll
        for (int mt = 0; mt < 2; ++mt)
          acc[mt][nt] = __builtin_amdgcn_mfma_f32_16x16x32_bf16(af[mt], bfrag, acc[mt][nt], 0, 0, 0);
      }
    }
  };

#pragma unroll 1
  for (int ith = 0; ith < 8; ++ith) {
    qstep(paA, 2 * ith);
    qstep(paB, 2 * ith + 1);
  }

  const float scale = 0.08838834764831845f;  // 128^-0.5
#pragma unroll
  for (int nt = 0; nt < 2; ++nt) {
    int dcol = wv * 32 + nt * 16 + l15;
    int p = dcol >> 1;
    float inv = powf(10000.0f, -(float)p / 64.0f);
#pragma unroll
    for (int mt = 0; mt < 2; ++mt) {
#pragma unroll
      for (int r = 0; r < 4; ++r) {
        int m = m0 + mt * 16 + quad * 4 + r;
        int t = m & (TSEQ - 1);
        float ang = (float)t * inv;
        float s, c; sincosf(ang, &s, &c);
        float val = acc[mt][nt][r];
        float partner = __shfl_xor(val, 1, 64);
        float o = (lane & 1) ? (val * c + partner * s) : (val * c - partner * s);
        qrot[(size_t)m * DH + dcol] = f2bf(o * scale);
      }
    }
  }
}

// ------- causal flash attention: units = (b, 128-row q-tile, <=8 k-tiles of 64 keys) -------
// Dispatch order reversed within each batch (largest/high-Q units first) so the
// second scheduling wave is filled by the SMALLEST units (LJF). Opart/ml are
// indexed by the LOGICAL unit id, so k_merge is unchanged.
__global__ __launch_bounds__(256, 2) void k_attn(const u16* __restrict__ qrot,
                                                 const u16* __restrict__ krot,
                                                 const u16* __restrict__ vt,
                                                 u16* __restrict__ Opart,
                                                 float2* __restrict__ ml) {
  __shared__ u16 Kl[16 * 64 * 8];
  __shared__ u16 Vl[8 * 128 * 8];
  __shared__ u16 Pl[4 * 32 * 72];

  int bid = blockIdx.x;                // 576 = 4 * 144
  int b = bid / 144;
  int u = 143 - (bid - b * 144);       // big-Q (longest) units dispatch first
  int uid = b * 144 + u;               // logical unit id for Opart/ml
  int Q = 0;
#pragma unroll 1
  for (int q = 31; q >= 0; --q) {
    if (unit_base(q) <= u) { Q = q; break; }
  }
  int kc = u - unit_base(Q);
  int nkt = 2 * Q + 2;
  int kt0 = kc * 8;
  int kt1 = min(kt0 + 8, nkt);
  int m0 = Q * 128;

  int tid = threadIdx.x;
  int w = tid >> 6;
  int lane = tid & 63;
  int l15 = lane & 15;
  int quad = lane >> 4;
  u16* pw = Pl + w * 32 * 72;

  int rK = tid & 63;   int jgK = tid >> 6;
  int dV = tid & 127;  int hV = tid >> 7;

  const u16* kb = krot + (size_t)b * TSEQ * DH;
  const u16* vb = vt + (size_t)b * DH * TSEQ;

  bf16x8 qf[2][4];
#pragma unroll
  for (int mt = 0; mt < 2; ++mt) {
    const u16* qb = qrot + ((size_t)(b * TSEQ + m0 + mt * 64 + w * 16 + l15)) * DH + quad * 8;
#pragma unroll
    for (int c = 0; c < 4; ++c) qf[mt][c] = ld_bf8(qb + c * 32);
  }

  f32x4 o_acc[2][8];
#pragma unroll
  for (int mt = 0; mt < 2; ++mt)
#pragma unroll
    for (int i = 0; i < 8; ++i) o_acc[mt][i] = (f32x4){0.f, 0.f, 0.f, 0.f};
  float m_st[2][4], l_st[2][4];
#pragma unroll
  for (int mt = 0; mt < 2; ++mt)
#pragma unroll
    for (int r = 0; r < 4; ++r) { m_st[mt][r] = -INFINITY; l_st[mt][r] = 0.f; }

  u16x8 kr[4], vr[4];
  {
    const u16* ks = kb + (size_t)(kt0 * 64 + rK) * DH + jgK * 32;
    const u16* vs = vb + (size_t)dV * TSEQ + kt0 * 64 + hV * 32;
#pragma unroll
    for (int i = 0; i < 4; ++i) { kr[i] = *(const u16x8*)(ks + i * 8); vr[i] = *(const u16x8*)(vs + i * 8); }
  }

  for (int kt = kt0; kt < kt1; ++kt) {
    lds_barrier();
#pragma unroll
    for (int i = 0; i < 4; ++i) {
      *(u16x8*)&Kl[((jgK * 4 + i) * 64 + rK) * 8] = kr[i];
      *(u16x8*)&Vl[((hV * 4 + i) * 128 + dV) * 8] = vr[i];
    }
    lds_barrier();
    if (kt + 1 < kt1) {
      const u16* ks = kb + (size_t)((kt + 1) * 64 + rK) * DH + jgK * 32;
      const u16* vs = vb + (size_t)dV * TSEQ + (kt + 1) * 64 + hV * 32;
#pragma unroll
      for (int i = 0; i < 4; ++i) { kr[i] = *(const u16x8*)(ks + i * 8); vr[i] = *(const u16x8*)(vs + i * 8); }
    }

    f32x4 s[2][4];
#pragma unroll
    for (int mt = 0; mt < 2; ++mt)
#pragma unroll
      for (int nt = 0; nt < 4; ++nt) s[mt][nt] = (f32x4){0.f, 0.f, 0.f, 0.f};
    __builtin_amdgcn_s_setprio(1);
#pragma unroll
    for (int c = 0; c < 4; ++c)
#pragma unroll
      for (int nt = 0; nt < 4; ++nt) {
        bf16x8 kf = ld_bf8(&Kl[((c * 4 + quad) * 64 + nt * 16 + l15) * 8]);
#pragma unroll
        for (int mt = 0; mt < 2; ++mt)
          s[mt][nt] = __builtin_amdgcn_mfma_f32_16x16x32_bf16(qf[mt][c], kf, s[mt][nt], 0, 0, 0);
      }
    __builtin_amdgcn_s_setprio(0);

    if (kt * 64 >= m0) {
#pragma unroll
      for (int mt = 0; mt < 2; ++mt)
#pragma unroll
        for (int nt = 0; nt < 4; ++nt)
#pragma unroll
          for (int r = 0; r < 4; ++r) {
            int key_g = kt * 64 + nt * 16 + l15;
            int row_g = m0 + mt * 64 + w * 16 + quad * 4 + r;
            if (key_g > row_g) s[mt][nt][r] = -INFINITY;
          }
    }

    float alpha[2][4];
    int chg = 0;
#pragma unroll
    for (int mt = 0; mt < 2; ++mt)
#pragma unroll
      for (int r = 0; r < 4; ++r) {
        float rm = fmaxf(fmaxf(s[mt][0][r], s[mt][1][r]), fmaxf(s[mt][2][r], s[mt][3][r]));
        rm = red_max16(rm);
        float mn = fmaxf(m_st[mt][r], rm);
        float al = __expf(m_st[mt][r] - mn);
        m_st[mt][r] = mn;
        float ps = 0.f;
#pragma unroll
        for (int nt = 0; nt < 4; ++nt) {
          float pv = __expf(s[mt][nt][r] - mn);
          s[mt][nt][r] = pv;
          ps += pv;
        }
        ps = red_sum16(ps);
        l_st[mt][r] = l_st[mt][r] * al + ps;
        alpha[mt][r] = al;
        chg |= (al != 1.0f);
      }
    if (__any(chg)) {
#pragma unroll
      for (int mt = 0; mt < 2; ++mt)
#pragma unroll
        for (int nt = 0; nt < 8; ++nt)
#pragma unroll
          for (int r = 0; r < 4; ++r) o_acc[mt][nt][r] *= alpha[mt][r];
    }

#pragma unroll
    for (int mt = 0; mt < 2; ++mt)
#pragma unroll
      for (int nt = 0; nt < 4; ++nt)
#pragma unroll
        for (int r = 0; r < 4; ++r)
          pw[(mt * 16 + quad * 4 + r) * 72 + nt * 16 + l15] = f2bf(s[mt][nt][r]);

#pragma unroll
    for (int c2 = 0; c2 < 2; ++c2) {
      bf16x8 pf[2];
#pragma unroll
      for (int mt = 0; mt < 2; ++mt)
        pf[mt] = ld_bf8(pw + (mt * 16 + l15) * 72 + c2 * 32 + quad * 8);
      __builtin_amdgcn_s_setprio(1);
#pragma unroll
      for (int nt = 0; nt < 8; ++nt) {
        bf16x8 vf = ld_bf8(&Vl[((c2 * 4 + quad) * 128 + nt * 16 + l15) * 8]);
#pragma unroll
        for (int mt = 0; mt < 2; ++mt)
          o_acc[mt][nt] = __builtin_amdgcn_mfma_f32_16x16x32_bf16(pf[mt], vf, o_acc[mt][nt], 0, 0, 0);
      }
      __builtin_amdgcn_s_setprio(0);
    }
  }

  u16* op = Opart + (size_t)uid * (128 * 128);
#pragma unroll
  for (int mt = 0; mt < 2; ++mt)
#pragma unroll
    for (int nt = 0; nt < 8; ++nt)
#pragma unroll
      for (int r = 0; r < 4; ++r)
        op[(mt * 64 + w * 16 + quad * 4 + r) * 128 + nt * 16 + l15] = f2bf(o_acc[mt][nt][r]);
  if (l15 == 0) {
#pragma unroll
    for (int mt = 0; mt < 2; ++mt)
#pragma unroll
      for (int r = 0; r < 4; ++r) {
        float2 p; p.x = m_st[mt][r]; p.y = l_st[mt][r];
        ml[(size_t)uid * 128 + mt * 64 + w * 16 + quad * 4 + r] = p;
      }
  }
}

// ------- merge partials: one block per (b, 128-row q-tile), vectorized -------
__global__ __launch_bounds__(256) void k_merge(const u16* __restrict__ Opart,
                                               const float2* __restrict__ ml,
                                               float* __restrict__ out) {
  __shared__ float wgt[8][128];
  __shared__ float invL[128];
  int bid = blockIdx.x;                // b*32 + Q
  int b = bid >> 5, Q = bid & 31;
  int C = (Q >> 2) + 1;
  int base = b * 144 + unit_base(Q);
  int tid = threadIdx.x;
  if (tid < 128) {
    float mv[8], lv[8];
    float M = -INFINITY;
    for (int c = 0; c < C; ++c) {
      float2 p = ml[(size_t)(base + c) * 128 + tid];
      mv[c] = p.x; lv[c] = p.y;
      M = fmaxf(M, p.x);
    }
    float L = 0.f;
    for (int c = 0; c < C; ++c) {
      float wv = __expf(mv[c] - M);
      wgt[c][tid] = wv;
      L += wv * lv[c];
    }
    invL[tid] = 1.f / L;
  }
  __syncthreads();
#pragma unroll
  for (int k = 0; k < 8; ++k) {
    int slot = tid + k * 256;          // 2048 slots of 8 elems (128x128)
    int row = slot >> 4;
    float acc[8];
#pragma unroll
    for (int j = 0; j < 8; ++j) acc[j] = 0.f;
    for (int c = 0; c < C; ++c) {
      u16x8 v = *(const u16x8*)&Opart[(size_t)(base + c) * (128 * 128) + slot * 8];
      float wv = wgt[c][row];
#pragma unroll
      for (int j = 0; j < 8; ++j) acc[j] += wv * bf2f(v[j]);
    }
    float il = invL[row];
    float4 o0, o1;
    o0.x = acc[0] * il; o0.y = acc[1] * il; o0.z = acc[2] * il; o0.w = acc[3] * il;
    o1.x = acc[4] * il; o1.y = acc[5] * il; o1.z = acc[6] * il; o1.w = acc[7] * il;
    float* op = out + ((size_t)(b * TSEQ + Q * 128 + row)) * DH + (slot & 15) * 8;
    *(float4*)op = o0;
    *(float4*)(op + 4) = o1;
  }
}

extern "C" void kernel_launch(void* const* d_in, const int* in_sizes, int n_in,
                              void* d_out, int out_size, void* d_ws, size_t ws_size,
                              hipStream_t stream) {
  const float* x     = (const float*)d_in[0];
  const float* key   = (const float*)d_in[1];
  const float* value = (const float*)d_in[2];
  const float* w_q   = (const float*)d_in[3];
  float* out = (float*)d_out;

  char* ws = (char*)d_ws;
  u16* qrot   = (u16*)(ws);                    // 4 MB
  u16* krot   = (u16*)(ws + (4u  << 20));      // 4 MB
  u16* vt     = (u16*)(ws + (8u  << 20));      // 4 MB
  u16* Opart  = (u16*)(ws + (12u << 20));      // 18.87 MB
  float2* ml  = (float2*)(ws + (31u << 20));   // 590 KB
  u16* wbf    = (u16*)(ws + (32u << 20));      // 512 KB

  k_wconv<<<256, 256, 0, stream>>>(w_q, wbf);
  // grid: 256 vt + 2048 ropek + 512 qproj
  k_fused1<<<2816, 256, 0, stream>>>(wbf, key, krot, value, vt, x, qrot);
  k_attn<<<NBATCH * 144, 256, 0, stream>>>(qrot, krot, vt, Opart, ml);
  k_merge<<<NBATCH * 32, 256, 0, stream>>>(Opart, ml, out);
}

// Round 6
// 292.772 us; speedup vs baseline: 1.5209x; 1.0377x over previous
//
#include <hip/hip_runtime.h>
#include <hip/hip_bf16.h>

#define TSEQ  4096
#define NBATCH 4
#define CDIM  2048
#define DH    128

typedef __bf16 bf16x8 __attribute__((ext_vector_type(8)));
typedef float  f32x4  __attribute__((ext_vector_type(4)));
typedef unsigned short u16x8 __attribute__((ext_vector_type(8)));
typedef unsigned       u32x4 __attribute__((ext_vector_type(4)));
typedef unsigned short u16;

__device__ __forceinline__ u16 f2bf(float f) {
  union { float f; unsigned u; } v; v.f = f;
  unsigned r = (v.u + 0x7FFFu + ((v.u >> 16) & 1u)) >> 16;
  return (u16)r;
}
__device__ __forceinline__ float bf2f(u16 h) {
  union { unsigned u; float f; } v; v.u = ((unsigned)h) << 16;
  return v.f;
}
__device__ __forceinline__ bf16x8 ld_bf8(const u16* p) {
  return __builtin_bit_cast(bf16x8, *(const u16x8*)p);
}
__device__ __forceinline__ unsigned pk2(float lo, float hi) {
  float2 f; f.x = lo; f.y = hi;
  __hip_bfloat162 h = __float22bfloat162_rn(f);
  unsigned r; __builtin_memcpy(&r, &h, 4);
  return r;
}
__device__ __forceinline__ u16x8 cvt8u(float4 a, float4 b) {
  u32x4 u;
  u[0] = pk2(a.x, a.y); u[1] = pk2(a.z, a.w);
  u[2] = pk2(b.x, b.y); u[3] = pk2(b.z, b.w);
  return __builtin_bit_cast(u16x8, u);
}

// raw workgroup barrier: drains LDS (lgkmcnt) only, NOT vmcnt — keeps global
// prefetch loads in flight across the barrier.
__device__ __forceinline__ void lds_barrier() {
  asm volatile("s_waitcnt lgkmcnt(0)" ::: "memory");
  __builtin_amdgcn_s_barrier();
}

// DPP cross-lane (VALU pipe): reduce over each 16-lane row
template<int CTRL>
__device__ __forceinline__ float dppmv(float x) {
  return __builtin_bit_cast(float,
    __builtin_amdgcn_update_dpp(0, __builtin_bit_cast(int, x), CTRL, 0xF, 0xF, true));
}
__device__ __forceinline__ float red_max16(float v) {
  v = fmaxf(v, dppmv<0xB1>(v));
  v = fmaxf(v, dppmv<0x4E>(v));
  v = fmaxf(v, dppmv<0x124>(v));
  v = fmaxf(v, dppmv<0x128>(v));
  return v;
}
__device__ __forceinline__ float red_sum16(float v) {
  v += dppmv<0xB1>(v);
  v += dppmv<0x4E>(v);
  v += dppmv<0x124>(v);
  v += dppmv<0x128>(v);
  return v;
}

// unit base within a batch: q-tile Q (128 rows) has (Q>>2)+1 chunks
__device__ __forceinline__ int unit_base(int Q) {
  int a = Q >> 2, bq = Q & 3;
  return 2 * a * (a + 1) + bq * (a + 1);
}

// ---------------- prep: vt | wconv | ropek (one launch, no qproj) ----------------
__global__ __launch_bounds__(256) void k_prep(const float* __restrict__ w, u16* __restrict__ wbf,
                                              const float* __restrict__ key, u16* __restrict__ krot,
                                              const float* __restrict__ value, u16* __restrict__ vt) {
  __shared__ u16 S[128 * 66];
  int bid = blockIdx.x;
  int tid = threadIdx.x;

  if (bid < 256) {
    // ---- value transpose [B,T,D] -> [B,D,T] in bf16 ----
    int b = bid >> 6;
    int t0 = (bid & 63) * 64;
    int d = (tid & 31) * 4;
    int tl0 = tid >> 5;
#pragma unroll
    for (int i = 0; i < 8; ++i) {
      int tl = tl0 + i * 8;
      const float4 val = *(const float4*)(value + ((size_t)(b * TSEQ + t0 + tl)) * DH + d);
      S[(d + 0) * 66 + tl] = f2bf(val.x);
      S[(d + 1) * 66 + tl] = f2bf(val.y);
      S[(d + 2) * 66 + tl] = f2bf(val.z);
      S[(d + 3) * 66 + tl] = f2bf(val.w);
    }
    __syncthreads();
#pragma unroll
    for (int i = 0; i < 16; ++i) {
      int idx = tid + i * 256;
      int dd = idx >> 5;
      int tw = (idx & 31) * 2;
      unsigned lo = S[dd * 66 + tw];
      unsigned hi = S[dd * 66 + tw + 1];
      *(unsigned*)(vt + ((size_t)(b * DH + dd)) * TSEQ + t0 + tw) = lo | (hi << 16);
    }
    return;
  }

  if (bid < 512) {
    // ---- w_q fp32 -> bf16 ----
    int i = (bid - 256) * 256 + tid;
    const float4 v = *(const float4*)(w + (size_t)i * 4);
    uint2 o; o.x = pk2(v.x, v.y); o.y = pk2(v.z, v.w);
    *(uint2*)(wbf + (size_t)i * 4) = o;
    return;
  }

  // ---- RoPE on key, 16 B/thread (2 pairs), fp32 -> bf16 ----
  int idx = (bid - 512) * 256 + tid;   // float4 index
  int f0 = idx * 4;
  int row = f0 >> 7;                   // /DH (floats per row)
  int d = f0 & 127;
  int p = d >> 1;                      // even pair index; handles p and p+1
  int t = row & (TSEQ - 1);
  const float4 kv = *(const float4*)(key + (size_t)row * DH + d);
  float inv0 = powf(10000.0f, -(float)p / 64.0f);
  float inv1 = powf(10000.0f, -(float)(p + 1) / 64.0f);
  float s0, c0, s1, c1;
  sincosf((float)t * inv0, &s0, &c0);
  sincosf((float)t * inv1, &s1, &c1);
  uint2 o;
  o.x = pk2(kv.x * c0 - kv.y * s0, kv.x * s0 + kv.y * c0);
  o.y = pk2(kv.z * c1 - kv.w * s1, kv.z * s1 + kv.w * c1);
  *(uint2*)(krot + (size_t)row * DH + d) = o;
}

// ------- q projection: 512-thread blocks, 32-row tiles, 8 waves N-parallel -------
// 512 blocks x 2/CU = 16 waves/CU = 4 waves/SIMD (2x the old latency hiding).
// Each wave owns 16 output cols (dcol = w*16+l15) -> block reads wbf exactly once.
// Staging: thread stages one 8-float chunk (32 B) -> ping-pong = 16 VGPRs only.
// LDS [chunk16][prow32][8] bf16 with prow = (row+chunk)&31 (validated swizzle).
__global__ __launch_bounds__(512, 4) void k_qproj(const float* __restrict__ x,
                                                  const u16* __restrict__ wbf,
                                                  u16* __restrict__ qrot) {
  __shared__ u16 Al[16 * 32 * 8];        // 8 KB
  int bid = blockIdx.x;
  int tid = threadIdx.x;
  int w = tid >> 6;                      // 0..7
  int lane = tid & 63;
  int l15 = lane & 15;
  int quad = lane >> 4;
  int m0 = bid * 32;
  int dcol = w * 16 + l15;

  int srow = tid >> 4;                   // 0..31
  int chunk = tid & 15;                  // 0..15
  int prow = (srow + chunk) & 31;
  const float* xg = x + (size_t)(m0 + srow) * CDIM + chunk * 8;
  const u16* wp = wbf + (size_t)dcol * CDIM + quad * 8;

  f32x4 acc[2];
  acc[0] = (f32x4){0.f, 0.f, 0.f, 0.f};
  acc[1] = (f32x4){0.f, 0.f, 0.f, 0.f};

  float4 paA[2], paB[2];
  paA[0] = *(const float4*)(xg);       paA[1] = *(const float4*)(xg + 4);
  paB[0] = *(const float4*)(xg + 128); paB[1] = *(const float4*)(xg + 132);

  auto qstep = [&](float4 (&pa)[2], int itc) {
    u16x8 st = cvt8u(pa[0], pa[1]);
    if (itc + 2 < CDIM / 128) {          // prefetch it+2 into the buffer just consumed
      const float* xn = xg + (size_t)(itc + 2) * 128;
      pa[0] = *(const float4*)xn;
      pa[1] = *(const float4*)(xn + 4);
    }
    lds_barrier();
    *(u16x8*)&Al[(chunk * 32 + prow) * 8] = st;
    lds_barrier();
    int k0 = itc * 128;
#pragma unroll
    for (int ks = 0; ks < 4; ++ks) {
      int ch = ks * 4 + quad;
      bf16x8 bfrag = ld_bf8(wp + k0 + ks * 32);
#pragma unroll
      for (int mt = 0; mt < 2; ++mt) {
        int rr = (mt * 16 + l15 + ch) & 31;
        bf16x8 af = ld_bf8(&Al[(ch * 32 + rr) * 8]);
        acc[mt] = __builtin_amdgcn_mfma_f32_16x16x32_bf16(af, bfrag, acc[mt], 0, 0, 0);
      }
    }
  };

#pragma unroll 1
  for (int ith = 0; ith < 8; ++ith) {
    qstep(paA, 2 * ith);
    qstep(paB, 2 * ith + 1);
  }

  const float scale = 0.08838834764831845f;  // 128^-0.5
  int p = dcol >> 1;
  float inv = powf(10000.0f, -(float)p / 64.0f);
#pragma unroll
  for (int mt = 0; mt < 2; ++mt) {
#pragma unroll
    for (int r = 0; r < 4; ++r) {
      int m = m0 + mt * 16 + quad * 4 + r;
      int t = m & (TSEQ - 1);
      float ang = (float)t * inv;
      float s, c; sincosf(ang, &s, &c);
      float val = acc[mt][r];
      float partner = __shfl_xor(val, 1, 64);
      float o = (lane & 1) ? (val * c + partner * s) : (val * c - partner * s);
      qrot[(size_t)m * DH + dcol] = f2bf(o * scale);
    }
  }
}

// ------- causal flash attention: units = (b, 128-row q-tile, <=8 k-tiles of 64 keys) -------
// Dispatch order reversed within each batch (largest/high-Q units first) so the
// second scheduling wave is filled by the SMALLEST units (LJF). Opart/ml are
// indexed by the LOGICAL unit id, so k_merge is unchanged.
__global__ __launch_bounds__(256, 2) void k_attn(const u16* __restrict__ qrot,
                                                 const u16* __restrict__ krot,
                                                 const u16* __restrict__ vt,
                                                 u16* __restrict__ Opart,
                                                 float2* __restrict__ ml) {
  __shared__ u16 Kl[16 * 64 * 8];
  __shared__ u16 Vl[8 * 128 * 8];
  __shared__ u16 Pl[4 * 32 * 72];

  int bid = blockIdx.x;                // 576 = 4 * 144
  int b = bid / 144;
  int u = 143 - (bid - b * 144);       // big-Q (longest) units dispatch first
  int uid = b * 144 + u;               // logical unit id for Opart/ml
  int Q = 0;
#pragma unroll 1
  for (int q = 31; q >= 0; --q) {
    if (unit_base(q) <= u) { Q = q; break; }
  }
  int kc = u - unit_base(Q);
  int nkt = 2 * Q + 2;
  int kt0 = kc * 8;
  int kt1 = min(kt0 + 8, nkt);
  int m0 = Q * 128;

  int tid = threadIdx.x;
  int w = tid >> 6;
  int lane = tid & 63;
  int l15 = lane & 15;
  int quad = lane >> 4;
  u16* pw = Pl + w * 32 * 72;

  int rK = tid & 63;   int jgK = tid >> 6;
  int dV = tid & 127;  int hV = tid >> 7;

  const u16* kb = krot + (size_t)b * TSEQ * DH;
  const u16* vb = vt + (size_t)b * DH * TSEQ;

  bf16x8 qf[2][4];
#pragma unroll
  for (int mt = 0; mt < 2; ++mt) {
    const u16* qb = qrot + ((size_t)(b * TSEQ + m0 + mt * 64 + w * 16 + l15)) * DH + quad * 8;
#pragma unroll
    for (int c = 0; c < 4; ++c) qf[mt][c] = ld_bf8(qb + c * 32);
  }

  f32x4 o_acc[2][8];
#pragma unroll
  for (int mt = 0; mt < 2; ++mt)
#pragma unroll
    for (int i = 0; i < 8; ++i) o_acc[mt][i] = (f32x4){0.f, 0.f, 0.f, 0.f};
  float m_st[2][4], l_st[2][4];
#pragma unroll
  for (int mt = 0; mt < 2; ++mt)
#pragma unroll
    for (int r = 0; r < 4; ++r) { m_st[mt][r] = -INFINITY; l_st[mt][r] = 0.f; }

  u16x8 kr[4], vr[4];
  {
    const u16* ks = kb + (size_t)(kt0 * 64 + rK) * DH + jgK * 32;
    const u16* vs = vb + (size_t)dV * TSEQ + kt0 * 64 + hV * 32;
#pragma unroll
    for (int i = 0; i < 4; ++i) { kr[i] = *(const u16x8*)(ks + i * 8); vr[i] = *(const u16x8*)(vs + i * 8); }
  }

  for (int kt = kt0; kt < kt1; ++kt) {
    lds_barrier();
#pragma unroll
    for (int i = 0; i < 4; ++i) {
      *(u16x8*)&Kl[((jgK * 4 + i) * 64 + rK) * 8] = kr[i];
      *(u16x8*)&Vl[((hV * 4 + i) * 128 + dV) * 8] = vr[i];
    }
    lds_barrier();
    if (kt + 1 < kt1) {
      const u16* ks = kb + (size_t)((kt + 1) * 64 + rK) * DH + jgK * 32;
      const u16* vs = vb + (size_t)dV * TSEQ + (kt + 1) * 64 + hV * 32;
#pragma unroll
      for (int i = 0; i < 4; ++i) { kr[i] = *(const u16x8*)(ks + i * 8); vr[i] = *(const u16x8*)(vs + i * 8); }
    }

    f32x4 s[2][4];
#pragma unroll
    for (int mt = 0; mt < 2; ++mt)
#pragma unroll
      for (int nt = 0; nt < 4; ++nt) s[mt][nt] = (f32x4){0.f, 0.f, 0.f, 0.f};
    __builtin_amdgcn_s_setprio(1);
#pragma unroll
    for (int c = 0; c < 4; ++c)
#pragma unroll
      for (int nt = 0; nt < 4; ++nt) {
        bf16x8 kf = ld_bf8(&Kl[((c * 4 + quad) * 64 + nt * 16 + l15) * 8]);
#pragma unroll
        for (int mt = 0; mt < 2; ++mt)
          s[mt][nt] = __builtin_amdgcn_mfma_f32_16x16x32_bf16(qf[mt][c], kf, s[mt][nt], 0, 0, 0);
      }
    __builtin_amdgcn_s_setprio(0);

    if (kt * 64 >= m0) {
#pragma unroll
      for (int mt = 0; mt < 2; ++mt)
#pragma unroll
        for (int nt = 0; nt < 4; ++nt)
#pragma unroll
          for (int r = 0; r < 4; ++r) {
            int key_g = kt * 64 + nt * 16 + l15;
            int row_g = m0 + mt * 64 + w * 16 + quad * 4 + r;
            if (key_g > row_g) s[mt][nt][r] = -INFINITY;
          }
    }

    float alpha[2][4];
    int chg = 0;
#pragma unroll
    for (int mt = 0; mt < 2; ++mt)
#pragma unroll
      for (int r = 0; r < 4; ++r) {
        float rm = fmaxf(fmaxf(s[mt][0][r], s[mt][1][r]), fmaxf(s[mt][2][r], s[mt][3][r]));
        rm = red_max16(rm);
        float mn = fmaxf(m_st[mt][r], rm);
        float al = __expf(m_st[mt][r] - mn);
        m_st[mt][r] = mn;
        float ps = 0.f;
#pragma unroll
        for (int nt = 0; nt < 4; ++nt) {
          float pv = __expf(s[mt][nt][r] - mn);
          s[mt][nt][r] = pv;
          ps += pv;
        }
        ps = red_sum16(ps);
        l_st[mt][r] = l_st[mt][r] * al + ps;
        alpha[mt][r] = al;
        chg |= (al != 1.0f);
      }
    if (__any(chg)) {
#pragma unroll
      for (int mt = 0; mt < 2; ++mt)
#pragma unroll
        for (int nt = 0; nt < 8; ++nt)
#pragma unroll
          for (int r = 0; r < 4; ++r) o_acc[mt][nt][r] *= alpha[mt][r];
    }

#pragma unroll
    for (int mt = 0; mt < 2; ++mt)
#pragma unroll
      for (int nt = 0; nt < 4; ++nt)
#pragma unroll
        for (int r = 0; r < 4; ++r)
          pw[(mt * 16 + quad * 4 + r) * 72 + nt * 16 + l15] = f2bf(s[mt][nt][r]);

#pragma unroll
    for (int c2 = 0; c2 < 2; ++c2) {
      bf16x8 pf[2];
#pragma unroll
      for (int mt = 0; mt < 2; ++mt)
        pf[mt] = ld_bf8(pw + (mt * 16 + l15) * 72 + c2 * 32 + quad * 8);
      __builtin_amdgcn_s_setprio(1);
#pragma unroll
      for (int nt = 0; nt < 8; ++nt) {
        bf16x8 vf = ld_bf8(&Vl[((c2 * 4 + quad) * 128 + nt * 16 + l15) * 8]);
#pragma unroll
        for (int mt = 0; mt < 2; ++mt)
          o_acc[mt][nt] = __builtin_amdgcn_mfma_f32_16x16x32_bf16(pf[mt], vf, o_acc[mt][nt], 0, 0, 0);
      }
      __builtin_amdgcn_s_setprio(0);
    }
  }

  u16* op = Opart + (size_t)uid * (128 * 128);
#pragma unroll
  for (int mt = 0; mt < 2; ++mt)
#pragma unroll
    for (int nt = 0; nt < 8; ++nt)
#pragma unroll
      for (int r = 0; r < 4; ++r)
        op[(mt * 64 + w * 16 + quad * 4 + r) * 128 + nt * 16 + l15] = f2bf(o_acc[mt][nt][r]);
  if (l15 == 0) {
#pragma unroll
    for (int mt = 0; mt < 2; ++mt)
#pragma unroll
      for (int r = 0; r < 4; ++r) {
        float2 p; p.x = m_st[mt][r]; p.y = l_st[mt][r];
        ml[(size_t)uid * 128 + mt * 64 + w * 16 + quad * 4 + r] = p;
      }
  }
}

// ------- merge partials: one block per (b, 128-row q-tile), vectorized -------
__global__ __launch_bounds__(256) void k_merge(const u16* __restrict__ Opart,
                                               const float2* __restrict__ ml,
                                               float* __restrict__ out) {
  __shared__ float wgt[8][128];
  __shared__ float invL[128];
  int bid = blockIdx.x;                // b*32 + Q
  int b = bid >> 5, Q = bid & 31;
  int C = (Q >> 2) + 1;
  int base = b * 144 + unit_base(Q);
  int tid = threadIdx.x;
  if (tid < 128) {
    float mv[8], lv[8];
    float M = -INFINITY;
    for (int c = 0; c < C; ++c) {
      float2 p = ml[(size_t)(base + c) * 128 + tid];
      mv[c] = p.x; lv[c] = p.y;
      M = fmaxf(M, p.x);
    }
    float L = 0.f;
    for (int c = 0; c < C; ++c) {
      float wv = __expf(mv[c] - M);
      wgt[c][tid] = wv;
      L += wv * lv[c];
    }
    invL[tid] = 1.f / L;
  }
  __syncthreads();
#pragma unroll
  for (int k = 0; k < 8; ++k) {
    int slot = tid + k * 256;          // 2048 slots of 8 elems (128x128)
    int row = slot >> 4;
    float acc[8];
#pragma unroll
    for (int j = 0; j < 8; ++j) acc[j] = 0.f;
    for (int c = 0; c < C; ++c) {
      u16x8 v = *(const u16x8*)&Opart[(size_t)(base + c) * (128 * 128) + slot * 8];
      float wv = wgt[c][row];
#pragma unroll
      for (int j = 0; j < 8; ++j) acc[j] += wv * bf2f(v[j]);
    }
    float il = invL[row];
    float4 o0, o1;
    o0.x = acc[0] * il; o0.y = acc[1] * il; o0.z = acc[2] * il; o0.w = acc[3] * il;
    o1.x = acc[4] * il; o1.y = acc[5] * il; o1.z = acc[6] * il; o1.w = acc[7] * il;
    float* op = out + ((size_t)(b * TSEQ + Q * 128 + row)) * DH + (slot & 15) * 8;
    *(float4*)op = o0;
    *(float4*)(op + 4) = o1;
  }
}

extern "C" void kernel_launch(void* const* d_in, const int* in_sizes, int n_in,
                              void* d_out, int out_size, void* d_ws, size_t ws_size,
                              hipStream_t stream) {
  const float* x     = (const float*)d_in[0];
  const float* key   = (const float*)d_in[1];
  const float* value = (const float*)d_in[2];
  const float* w_q   = (const float*)d_in[3];
  float* out = (float*)d_out;

  char* ws = (char*)d_ws;
  u16* qrot   = (u16*)(ws);                    // 4 MB
  u16* krot   = (u16*)(ws + (4u  << 20));      // 4 MB
  u16* vt     = (u16*)(ws + (8u  << 20));      // 4 MB
  u16* Opart  = (u16*)(ws + (12u << 20));      // 18.87 MB
  float2* ml  = (float2*)(ws + (31u << 20));   // 590 KB
  u16* wbf    = (u16*)(ws + (32u << 20));      // 512 KB

  // grid: 256 vt + 256 wconv + 2048 ropek
  k_prep<<<2560, 256, 0, stream>>>(w_q, wbf, key, krot, value, vt);
  k_qproj<<<(NBATCH * TSEQ) / 32, 512, 0, stream>>>(x, wbf, qrot);
  k_attn<<<NBATCH * 144, 256, 0, stream>>>(qrot, krot, vt, Opart, ml);
  k_merge<<<NBATCH * 32, 256, 0, stream>>>(Opart, ml, out);
}

// Round 8
// 284.694 us; speedup vs baseline: 1.5640x; 1.0284x over previous
//
#include <hip/hip_runtime.h>
#include <hip/hip_bf16.h>

#define TSEQ  4096
#define NBATCH 4
#define CDIM  2048
#define DH    128

typedef __bf16 bf16x8 __attribute__((ext_vector_type(8)));
typedef float  f32x4  __attribute__((ext_vector_type(4)));
typedef unsigned short u16x8 __attribute__((ext_vector_type(8)));
typedef unsigned       u32x4 __attribute__((ext_vector_type(4)));
typedef unsigned short u16;

__device__ __forceinline__ u16 f2bf(float f) {
  union { float f; unsigned u; } v; v.f = f;
  unsigned r = (v.u + 0x7FFFu + ((v.u >> 16) & 1u)) >> 16;
  return (u16)r;
}
__device__ __forceinline__ float bf2f(u16 h) {
  union { unsigned u; float f; } v; v.u = ((unsigned)h) << 16;
  return v.f;
}
__device__ __forceinline__ bf16x8 ld_bf8(const u16* p) {
  return __builtin_bit_cast(bf16x8, *(const u16x8*)p);
}
__device__ __forceinline__ unsigned pk2(float lo, float hi) {
  float2 f; f.x = lo; f.y = hi;
  __hip_bfloat162 h = __float22bfloat162_rn(f);
  unsigned r; __builtin_memcpy(&r, &h, 4);
  return r;
}
__device__ __forceinline__ u16x8 cvt8u(float4 a, float4 b) {
  u32x4 u;
  u[0] = pk2(a.x, a.y); u[1] = pk2(a.z, a.w);
  u[2] = pk2(b.x, b.y); u[3] = pk2(b.z, b.w);
  return __builtin_bit_cast(u16x8, u);
}

// direct global->LDS DMA, 16 B per lane. LDS dest = wave-uniform base + lane*16
// (linear); global src is per-lane (pre-swizzled there).
__device__ __forceinline__ void gload16(const void* g, void* l) {
  __builtin_amdgcn_global_load_lds(
      (const __attribute__((address_space(1))) unsigned*)g,
      (__attribute__((address_space(3))) unsigned*)l, 16, 0, 0);
}

// raw workgroup barrier: drains LDS (lgkmcnt) only, NOT vmcnt — keeps global
// prefetch loads in flight across the barrier. (Used in k_attn only.)
__device__ __forceinline__ void lds_barrier() {
  asm volatile("s_waitcnt lgkmcnt(0)" ::: "memory");
  __builtin_amdgcn_s_barrier();
}

// DPP cross-lane (VALU pipe): reduce over each 16-lane row
template<int CTRL>
__device__ __forceinline__ float dppmv(float x) {
  return __builtin_bit_cast(float,
    __builtin_amdgcn_update_dpp(0, __builtin_bit_cast(int, x), CTRL, 0xF, 0xF, true));
}
__device__ __forceinline__ float red_max16(float v) {
  v = fmaxf(v, dppmv<0xB1>(v));
  v = fmaxf(v, dppmv<0x4E>(v));
  v = fmaxf(v, dppmv<0x124>(v));
  v = fmaxf(v, dppmv<0x128>(v));
  return v;
}
__device__ __forceinline__ float red_sum16(float v) {
  v += dppmv<0xB1>(v);
  v += dppmv<0x4E>(v);
  v += dppmv<0x124>(v);
  v += dppmv<0x128>(v);
  return v;
}

// unit base within a batch: q-tile Q (128 rows) has (Q>>2)+1 chunks
__device__ __forceinline__ int unit_base(int Q) {
  int a = Q >> 2, bq = Q & 3;
  return 2 * a * (a + 1) + bq * (a + 1);
}

// ---------------- prep: vt | wconv | ropek (one launch, no qproj) ----------------
__global__ __launch_bounds__(256) void k_prep(const float* __restrict__ w, u16* __restrict__ wbf,
                                              const float* __restrict__ key, u16* __restrict__ krot,
                                              const float* __restrict__ value, u16* __restrict__ vt) {
  __shared__ u16 S[128 * 66];
  int bid = blockIdx.x;
  int tid = threadIdx.x;

  if (bid < 256) {
    int b = bid >> 6;
    int t0 = (bid & 63) * 64;
    int d = (tid & 31) * 4;
    int tl0 = tid >> 5;
#pragma unroll
    for (int i = 0; i < 8; ++i) {
      int tl = tl0 + i * 8;
      const float4 val = *(const float4*)(value + ((size_t)(b * TSEQ + t0 + tl)) * DH + d);
      S[(d + 0) * 66 + tl] = f2bf(val.x);
      S[(d + 1) * 66 + tl] = f2bf(val.y);
      S[(d + 2) * 66 + tl] = f2bf(val.z);
      S[(d + 3) * 66 + tl] = f2bf(val.w);
    }
    __syncthreads();
#pragma unroll
    for (int i = 0; i < 16; ++i) {
      int idx = tid + i * 256;
      int dd = idx >> 5;
      int tw = (idx & 31) * 2;
      unsigned lo = S[dd * 66 + tw];
      unsigned hi = S[dd * 66 + tw + 1];
      *(unsigned*)(vt + ((size_t)(b * DH + dd)) * TSEQ + t0 + tw) = lo | (hi << 16);
    }
    return;
  }

  if (bid < 512) {
    int i = (bid - 256) * 256 + tid;
    const float4 v = *(const float4*)(w + (size_t)i * 4);
    uint2 o; o.x = pk2(v.x, v.y); o.y = pk2(v.z, v.w);
    *(uint2*)(wbf + (size_t)i * 4) = o;
    return;
  }

  int idx = (bid - 512) * 256 + tid;   // float4 index
  int f0 = idx * 4;
  int row = f0 >> 7;
  int d = f0 & 127;
  int p = d >> 1;
  int t = row & (TSEQ - 1);
  const float4 kv = *(const float4*)(key + (size_t)row * DH + d);
  float inv0 = powf(10000.0f, -(float)p / 64.0f);
  float inv1 = powf(10000.0f, -(float)(p + 1) / 64.0f);
  float s0, c0, s1, c1;
  sincosf((float)t * inv0, &s0, &c0);
  sincosf((float)t * inv1, &s1, &c1);
  uint2 o;
  o.x = pk2(kv.x * c0 - kv.y * s0, kv.x * s0 + kv.y * c0);
  o.y = pk2(kv.z * c1 - kv.w * s1, kv.z * s1 + kv.w * c1);
  *(uint2*)(krot + (size_t)row * DH + d) = o;
}

// ------- q projection v3b: global_load_lds DMA staging, single __syncthreads/iter -------
// 512 blocks x 512 threads, 4 blocks/CU. x staged fp32 direct to LDS (no VGPR
// round-trip, no ds_write). Double-buffered [2][32][128] fp32 (32 KB). Per iter:
// issue next tile's 2 DMA loads FIRST (overlap whole compute phase), compute
// current tile (bfr regs preloaded last iter), prefetch next bfr regs, then one
// __syncthreads (its vmcnt(0) drain lands after the loads had the full compute
// phase to complete). Bank swizzle: 16B-granule XOR ((row&7)<<4) applied on the
// GLOBAL source (DMA writes LDS linearly) and on the ds_read address — an
// involution applied both-sides-or-neither. 16 lanes -> 2-way (free) on reads.
// fp32->bf16 cvt moved after the LDS read: same pk2 pairs, same order ->
// bit-identical fragments and accumulation order.
__global__ __launch_bounds__(512, 4) void k_qproj(const float* __restrict__ x,
                                                  const u16* __restrict__ wbf,
                                                  u16* __restrict__ qrot) {
  __shared__ float Al[2][32 * 128];      // 32 KB
  int bid = blockIdx.x;
  int tid = threadIdx.x;
  int w = tid >> 6;                      // 0..7
  int lane = tid & 63;
  int l15 = lane & 15;
  int quad = lane >> 4;
  int m0 = bid * 32;
  int dcol = w * 16 + l15;

  // staging: wave w owns rows 4w..4w+3; instr A = rows 4w+(lane>>5), B = +2
  int rA = 4 * w + (lane >> 5);
  int rB = rA + 2;
  const char* gA = (const char*)(x + (size_t)(m0 + rA) * CDIM) + (((lane & 31) * 16) ^ ((rA & 7) << 4));
  const char* gB = (const char*)(x + (size_t)(m0 + rB) * CDIM) + (((lane & 31) * 16) ^ ((rB & 7) << 4));
  char* lA0 = (char*)&Al[0][0] + (4 * w) * 512;   // rows 4w,4w+1 (1 KB)
  char* lB0 = lA0 + 1024;                          // rows 4w+2,4w+3

  const u16* wp = wbf + (size_t)dcol * CDIM + quad * 8;

  f32x4 acc[2];
  acc[0] = (f32x4){0.f, 0.f, 0.f, 0.f};
  acc[1] = (f32x4){0.f, 0.f, 0.f, 0.f};

  // prologue: stage tile 0, load bfrag 0, sync
  gload16(gA, lA0);
  gload16(gB, lB0);
  bf16x8 bfr[4];
#pragma unroll
  for (int ks = 0; ks < 4; ++ks) bfr[ks] = ld_bf8(wp + ks * 32);
  __syncthreads();

#pragma unroll 1
  for (int it = 0; it < CDIM / 128; ++it) {
    if (it + 1 < CDIM / 128) {           // issue next tile first — overlaps compute
      int nb = (it + 1) & 1;
      gload16(gA + (size_t)(it + 1) * 512, lA0 + nb * 16384);
      gload16(gB + (size_t)(it + 1) * 512, lB0 + nb * 16384);
    }

    const char* tile = (const char*)&Al[0][0] + (it & 1) * 16384;
#pragma unroll
    for (int ks = 0; ks < 4; ++ks) {
      int cbase = ks * 128 + quad * 32;
#pragma unroll
      for (int mt = 0; mt < 2; ++mt) {
        int row = mt * 16 + l15;
        int xr = (row & 7) << 4;
        float4 f0 = *(const float4*)(tile + row * 512 + (cbase ^ xr));
        float4 f1 = *(const float4*)(tile + row * 512 + ((cbase + 16) ^ xr));
        bf16x8 af = __builtin_bit_cast(bf16x8, cvt8u(f0, f1));
        acc[mt] = __builtin_amdgcn_mfma_f32_16x16x32_bf16(af, bfr[ks], acc[mt], 0, 0, 0);
      }
    }
    if (it + 1 < CDIM / 128) {
#pragma unroll
      for (int ks = 0; ks < 4; ++ks) bfr[ks] = ld_bf8(wp + (it + 1) * 128 + ks * 32);
    }
    __syncthreads();                     // drains vmcnt: next tile landed; buffer swap safe
  }

  const float scale = 0.08838834764831845f;  // 128^-0.5
  int p = dcol >> 1;
  float inv = powf(10000.0f, -(float)p / 64.0f);
#pragma unroll
  for (int mt = 0; mt < 2; ++mt) {
#pragma unroll
    for (int r = 0; r < 4; ++r) {
      int m = m0 + mt * 16 + quad * 4 + r;
      int t = m & (TSEQ - 1);
      float ang = (float)t * inv;
      float s, c; sincosf(ang, &s, &c);
      float val = acc[mt][r];
      float partner = __shfl_xor(val, 1, 64);
      float o = (lane & 1) ? (val * c + partner * s) : (val * c - partner * s);
      qrot[(size_t)m * DH + dcol] = f2bf(o * scale);
    }
  }
}

// ------- causal flash attention: units = (b, 128-row q-tile, <=8 k-tiles of 64 keys) -------
__global__ __launch_bounds__(256, 2) void k_attn(const u16* __restrict__ qrot,
                                                 const u16* __restrict__ krot,
                                                 const u16* __restrict__ vt,
                                                 u16* __restrict__ Opart,
                                                 float2* __restrict__ ml) {
  __shared__ u16 Kl[16 * 64 * 8];
  __shared__ u16 Vl[8 * 128 * 8];
  __shared__ u16 Pl[4 * 32 * 72];

  int bid = blockIdx.x;                // 576 = 4 * 144
  int b = bid / 144;
  int u = 143 - (bid - b * 144);       // big-Q (longest) units dispatch first
  int uid = b * 144 + u;               // logical unit id for Opart/ml
  int Q = 0;
#pragma unroll 1
  for (int q = 31; q >= 0; --q) {
    if (unit_base(q) <= u) { Q = q; break; }
  }
  int kc = u - unit_base(Q);
  int nkt = 2 * Q + 2;
  int kt0 = kc * 8;
  int kt1 = min(kt0 + 8, nkt);
  int m0 = Q * 128;

  int tid = threadIdx.x;
  int w = tid >> 6;
  int lane = tid & 63;
  int l15 = lane & 15;
  int quad = lane >> 4;
  u16* pw = Pl + w * 32 * 72;

  int rK = tid & 63;   int jgK = tid >> 6;
  int dV = tid & 127;  int hV = tid >> 7;

  const u16* kb = krot + (size_t)b * TSEQ * DH;
  const u16* vb = vt + (size_t)b * DH * TSEQ;

  bf16x8 qf[2][4];
#pragma unroll
  for (int mt = 0; mt < 2; ++mt) {
    const u16* qb = qrot + ((size_t)(b * TSEQ + m0 + mt * 64 + w * 16 + l15)) * DH + quad * 8;
#pragma unroll
    for (int c = 0; c < 4; ++c) qf[mt][c] = ld_bf8(qb + c * 32);
  }

  f32x4 o_acc[2][8];
#pragma unroll
  for (int mt = 0; mt < 2; ++mt)
#pragma unroll
    for (int i = 0; i < 8; ++i) o_acc[mt][i] = (f32x4){0.f, 0.f, 0.f, 0.f};
  float m_st[2][4], l_st[2][4];
#pragma unroll
  for (int mt = 0; mt < 2; ++mt)
#pragma unroll
    for (int r = 0; r < 4; ++r) { m_st[mt][r] = -INFINITY; l_st[mt][r] = 0.f; }

  u16x8 kr[4], vr[4];
  {
    const u16* ks = kb + (size_t)(kt0 * 64 + rK) * DH + jgK * 32;
    const u16* vs = vb + (size_t)dV * TSEQ + kt0 * 64 + hV * 32;
#pragma unroll
    for (int i = 0; i < 4; ++i) { kr[i] = *(const u16x8*)(ks + i * 8); vr[i] = *(const u16x8*)(vs + i * 8); }
  }

  for (int kt = kt0; kt < kt1; ++kt) {
    lds_barrier();
#pragma unroll
    for (int i = 0; i < 4; ++i) {
      *(u16x8*)&Kl[((jgK * 4 + i) * 64 + rK) * 8] = kr[i];
      *(u16x8*)&Vl[((hV * 4 + i) * 128 + dV) * 8] = vr[i];
    }
    lds_barrier();
    if (kt + 1 < kt1) {
      const u16* ks = kb + (size_t)((kt + 1) * 64 + rK) * DH + jgK * 32;
      const u16* vs = vb + (size_t)dV * TSEQ + (kt + 1) * 64 + hV * 32;
#pragma unroll
      for (int i = 0; i < 4; ++i) { kr[i] = *(const u16x8*)(ks + i * 8); vr[i] = *(const u16x8*)(vs + i * 8); }
    }

    f32x4 s[2][4];
#pragma unroll
    for (int mt = 0; mt < 2; ++mt)
#pragma unroll
      for (int nt = 0; nt < 4; ++nt) s[mt][nt] = (f32x4){0.f, 0.f, 0.f, 0.f};
    __builtin_amdgcn_s_setprio(1);
#pragma unroll
    for (int c = 0; c < 4; ++c)
#pragma unroll
      for (int nt = 0; nt < 4; ++nt) {
        bf16x8 kf = ld_bf8(&Kl[((c * 4 + quad) * 64 + nt * 16 + l15) * 8]);
#pragma unroll
        for (int mt = 0; mt < 2; ++mt)
          s[mt][nt] = __builtin_amdgcn_mfma_f32_16x16x32_bf16(qf[mt][c], kf, s[mt][nt], 0, 0, 0);
      }
    __builtin_amdgcn_s_setprio(0);

    if (kt * 64 >= m0) {
#pragma unroll
      for (int mt = 0; mt < 2; ++mt)
#pragma unroll
        for (int nt = 0; nt < 4; ++nt)
#pragma unroll
          for (int r = 0; r < 4; ++r) {
            int key_g = kt * 64 + nt * 16 + l15;
            int row_g = m0 + mt * 64 + w * 16 + quad * 4 + r;
            if (key_g > row_g) s[mt][nt][r] = -INFINITY;
          }
    }

    float alpha[2][4];
    int chg = 0;
#pragma unroll
    for (int mt = 0; mt < 2; ++mt)
#pragma unroll
      for (int r = 0; r < 4; ++r) {
        float rm = fmaxf(fmaxf(s[mt][0][r], s[mt][1][r]), fmaxf(s[mt][2][r], s[mt][3][r]));
        rm = red_max16(rm);
        float mn = fmaxf(m_st[mt][r], rm);
        float al = __expf(m_st[mt][r] - mn);
        m_st[mt][r] = mn;
        float ps = 0.f;
#pragma unroll
        for (int nt = 0; nt < 4; ++nt) {
          float pv = __expf(s[mt][nt][r] - mn);
          s[mt][nt][r] = pv;
          ps += pv;
        }
        ps = red_sum16(ps);
        l_st[mt][r] = l_st[mt][r] * al + ps;
        alpha[mt][r] = al;
        chg |= (al != 1.0f);
      }
    if (__any(chg)) {
#pragma unroll
      for (int mt = 0; mt < 2; ++mt)
#pragma unroll
        for (int nt = 0; nt < 8; ++nt)
#pragma unroll
          for (int r = 0; r < 4; ++r) o_acc[mt][nt][r] *= alpha[mt][r];
    }

#pragma unroll
    for (int mt = 0; mt < 2; ++mt)
#pragma unroll
      for (int nt = 0; nt < 4; ++nt)
#pragma unroll
        for (int r = 0; r < 4; ++r)
          pw[(mt * 16 + quad * 4 + r) * 72 + nt * 16 + l15] = f2bf(s[mt][nt][r]);

#pragma unroll
    for (int c2 = 0; c2 < 2; ++c2) {
      bf16x8 pf[2];
#pragma unroll
      for (int mt = 0; mt < 2; ++mt)
        pf[mt] = ld_bf8(pw + (mt * 16 + l15) * 72 + c2 * 32 + quad * 8);
      __builtin_amdgcn_s_setprio(1);
#pragma unroll
      for (int nt = 0; nt < 8; ++nt) {
        bf16x8 vf = ld_bf8(&Vl[((c2 * 4 + quad) * 128 + nt * 16 + l15) * 8]);
#pragma unroll
        for (int mt = 0; mt < 2; ++mt)
          o_acc[mt][nt] = __builtin_amdgcn_mfma_f32_16x16x32_bf16(pf[mt], vf, o_acc[mt][nt], 0, 0, 0);
      }
      __builtin_amdgcn_s_setprio(0);
    }
  }

  u16* op = Opart + (size_t)uid * (128 * 128);
#pragma unroll
  for (int mt = 0; mt < 2; ++mt)
#pragma unroll
    for (int nt = 0; nt < 8; ++nt)
#pragma unroll
      for (int r = 0; r < 4; ++r)
        op[(mt * 64 + w * 16 + quad * 4 + r) * 128 + nt * 16 + l15] = f2bf(o_acc[mt][nt][r]);
  if (l15 == 0) {
#pragma unroll
    for (int mt = 0; mt < 2; ++mt)
#pragma unroll
      for (int r = 0; r < 4; ++r) {
        float2 p; p.x = m_st[mt][r]; p.y = l_st[mt][r];
        ml[(size_t)uid * 128 + mt * 64 + w * 16 + quad * 4 + r] = p;
      }
  }
}

// ------- merge partials: one block per (b, 128-row q-tile), vectorized -------
__global__ __launch_bounds__(256) void k_merge(const u16* __restrict__ Opart,
                                               const float2* __restrict__ ml,
                                               float* __restrict__ out) {
  __shared__ float wgt[8][128];
  __shared__ float invL[128];
  int bid = blockIdx.x;                // b*32 + Q
  int b = bid >> 5, Q = bid & 31;
  int C = (Q >> 2) + 1;
  int base = b * 144 + unit_base(Q);
  int tid = threadIdx.x;
  if (tid < 128) {
    float mv[8], lv[8];
    float M = -INFINITY;
    for (int c = 0; c < C; ++c) {
      float2 p = ml[(size_t)(base + c) * 128 + tid];
      mv[c] = p.x; lv[c] = p.y;
      M = fmaxf(M, p.x);
    }
    float L = 0.f;
    for (int c = 0; c < C; ++c) {
      float wv = __expf(mv[c] - M);
      wgt[c][tid] = wv;
      L += wv * lv[c];
    }
    invL[tid] = 1.f / L;
  }
  __syncthreads();
#pragma unroll
  for (int k = 0; k < 8; ++k) {
    int slot = tid + k * 256;          // 2048 slots of 8 elems (128x128)
    int row = slot >> 4;
    float acc[8];
#pragma unroll
    for (int j = 0; j < 8; ++j) acc[j] = 0.f;
    for (int c = 0; c < C; ++c) {
      u16x8 v = *(const u16x8*)&Opart[(size_t)(base + c) * (128 * 128) + slot * 8];
      float wv = wgt[c][row];
#pragma unroll
      for (int j = 0; j < 8; ++j) acc[j] += wv * bf2f(v[j]);
    }
    float il = invL[row];
    float4 o0, o1;
    o0.x = acc[0] * il; o0.y = acc[1] * il; o0.z = acc[2] * il; o0.w = acc[3] * il;
    o1.x = acc[4] * il; o1.y = acc[5] * il; o1.z = acc[6] * il; o1.w = acc[7] * il;
    float* op = out + ((size_t)(b * TSEQ + Q * 128 + row)) * DH + (slot & 15) * 8;
    *(float4*)op = o0;
    *(float4*)(op + 4) = o1;
  }
}

extern "C" void kernel_launch(void* const* d_in, const int* in_sizes, int n_in,
                              void* d_out, int out_size, void* d_ws, size_t ws_size,
                              hipStream_t stream) {
  const float* x     = (const float*)d_in[0];
  const float* key   = (const float*)d_in[1];
  const float* value = (const float*)d_in[2];
  const float* w_q   = (const float*)d_in[3];
  float* out = (float*)d_out;

  char* ws = (char*)d_ws;
  u16* qrot   = (u16*)(ws);                    // 4 MB
  u16* krot   = (u16*)(ws + (4u  << 20));      // 4 MB
  u16* vt     = (u16*)(ws + (8u  << 20));      // 4 MB
  u16* Opart  = (u16*)(ws + (12u << 20));      // 18.87 MB
  float2* ml  = (float2*)(ws + (31u << 20));   // 590 KB
  u16* wbf    = (u16*)(ws + (32u << 20));      // 512 KB

  k_prep<<<2560, 256, 0, stream>>>(w_q, wbf, key, krot, value, vt);
  k_qproj<<<(NBATCH * TSEQ) / 32, 512, 0, stream>>>(x, wbf, qrot);
  k_attn<<<NBATCH * 144, 256, 0, stream>>>(qrot, krot, vt, Opart, ml);
  k_merge<<<NBATCH * 32, 256, 0, stream>>>(Opart, ml, out);
}